// Round 1
// baseline (1018.824 us; speedup 1.0000x reference)
//
#include <hip/hip_runtime.h>
#include <hip/hip_bf16.h>

// Problem: AttentionBlock  B=8, C=512, H=W=32 (S=1024), heads=8, hd=64, groups=32
// Pipeline: GroupNorm -> QKV 1x1conv -> attention over S -> proj 1x1conv + residual
//
// Round 0: correct fp32 baseline.
//   gn_stats:   per-(b,g) mean/rstd -> per-(b,c) affine scaleA/shiftB
//   qkv_gemm:   [1536x512] x [512x1024] per batch, GN affine fused into X load
//   attn:       flash-style, 64-query blocks, 32-key LDS tiles, online softmax,
//               output written in-place over the q region of the qkv buffer
//   proj_gemm:  [512x512] x [512x1024] per batch + bias + residual -> d_out

#define BATCH 8
#define C 512
#define S 1024
#define HEADS 8
#define HD 64
#define GROUPS 32
#define CPG 16          // channels per group
#define OC3 1536        // 3*C

__global__ __launch_bounds__(256) void gn_stats(
    const float* __restrict__ X, const float* __restrict__ nw,
    const float* __restrict__ nb, float* __restrict__ scaleA,
    float* __restrict__ shiftB)
{
    const int blk = blockIdx.x;         // b*32 + g
    const int bi = blk >> 5, g = blk & 31;
    const int tid = threadIdx.x;
    const size_t base = ((size_t)bi * C + g * CPG) * S;   // 16384 contiguous floats
    float s = 0.f, ss = 0.f;
    for (int i = tid; i < CPG * S; i += 256) {
        float v = X[base + i];
        s += v; ss += v * v;
    }
    __shared__ float rs[256], rss[256];
    rs[tid] = s; rss[tid] = ss;
    __syncthreads();
    for (int off = 128; off > 0; off >>= 1) {
        if (tid < off) { rs[tid] += rs[tid + off]; rss[tid] += rss[tid + off]; }
        __syncthreads();
    }
    __shared__ float sh_mean, sh_rstd;
    if (tid == 0) {
        float mean = rs[0] * (1.f / (CPG * S));
        float var = rss[0] * (1.f / (CPG * S)) - mean * mean;
        sh_mean = mean;
        sh_rstd = rsqrtf(var + 1e-5f);
    }
    __syncthreads();
    if (tid < CPG) {
        int c = g * CPG + tid;
        float rw = sh_rstd * nw[c];
        scaleA[bi * C + c] = rw;
        shiftB[bi * C + c] = nb[c] - sh_mean * rw;
    }
}

// out[b][o][s] = sum_c W[o][c] * (X[b][c][s]*scaleA[b][c] + shiftB[b][c]) + bias[o]
// grid: (S/64, 1536/64, B), block (16,16). 64x64 tile, BK=16, 4x4 reg blocking.
__global__ __launch_bounds__(256) void qkv_gemm(
    const float* __restrict__ X, const float* __restrict__ W,
    const float* __restrict__ bias, const float* __restrict__ scaleA,
    const float* __restrict__ shiftB, float* __restrict__ out)
{
    const int tx = threadIdx.x, ty = threadIdx.y;
    const int tid = ty * 16 + tx;
    const int s0 = blockIdx.x * 64;
    const int o0 = blockIdx.y * 64;
    const int bi = blockIdx.z;

    __shared__ float Ws[16][65];   // [k][m]
    __shared__ float Xs[16][65];   // [k][n]

    float acc[4][4];
    #pragma unroll
    for (int i = 0; i < 4; ++i)
        #pragma unroll
        for (int j = 0; j < 4; ++j) acc[i][j] = 0.f;

    const int wk = tid & 15, wm = tid >> 4;      // W-load: k fast, 16 m per pass
    const int xn = tid & 63, xk = tid >> 6;      // X-load: n fast, 4 k per pass

    for (int k0 = 0; k0 < C; k0 += 16) {
        __syncthreads();
        #pragma unroll
        for (int p = 0; p < 4; ++p) {
            int m = wm + p * 16;
            Ws[wk][m] = W[(size_t)(o0 + m) * C + k0 + wk];
        }
        #pragma unroll
        for (int p = 0; p < 4; ++p) {
            int k = xk + p * 4;
            int c = k0 + k;
            float sa = scaleA[bi * C + c];
            float sb = shiftB[bi * C + c];
            float x = X[((size_t)bi * C + c) * S + s0 + xn];
            Xs[k][xn] = x * sa + sb;
        }
        __syncthreads();
        #pragma unroll
        for (int kk = 0; kk < 16; ++kk) {
            float a[4], b[4];
            #pragma unroll
            for (int i = 0; i < 4; ++i) a[i] = Ws[kk][ty + 16 * i];
            #pragma unroll
            for (int j = 0; j < 4; ++j) b[j] = Xs[kk][tx + 16 * j];
            #pragma unroll
            for (int i = 0; i < 4; ++i)
                #pragma unroll
                for (int j = 0; j < 4; ++j) acc[i][j] += a[i] * b[j];
        }
    }
    #pragma unroll
    for (int i = 0; i < 4; ++i) {
        int o = o0 + ty + 16 * i;
        float bv = bias[o];
        #pragma unroll
        for (int j = 0; j < 4; ++j)
            out[((size_t)bi * OC3 + o) * S + s0 + tx + 16 * j] = acc[i][j] + bv;
    }
}

// Flash attention. grid (16 qblocks, 8 heads, 8 batch), 256 threads.
// thread (q = tid>>2, kq = tid&3): 8 scores per 32-key tile, 16 out-dims.
__global__ __launch_bounds__(256) void attn_kernel(float* __restrict__ qkv)
{
    const int qb = blockIdx.x, h = blockIdx.y, bi = blockIdx.z;
    const int tid = threadIdx.x;
    const int q = tid >> 2, kq = tid & 3;
    const int q0 = qb * 64;

    float* qp = qkv + ((size_t)bi * OC3 + h * HD) * S;
    const float* kp = qkv + ((size_t)bi * OC3 + C + h * HD) * S;
    const float* vp = qkv + ((size_t)bi * OC3 + 2 * C + h * HD) * S;

    __shared__ float qs[64][64];   // [d][q]
    __shared__ float ks[64][33];   // [d][k]
    __shared__ float vs[64][33];   // [d][k]
    __shared__ float ps[64][33];   // [q][k]

    const float scale = 0.125f;    // 1/sqrt(64)
    for (int idx = tid; idx < 64 * 64; idx += 256) {
        int d = idx >> 6, sq = idx & 63;
        qs[d][sq] = qp[(size_t)d * S + q0 + sq] * scale;
    }

    float m = -INFINITY, l = 0.f;
    float acc[16];
    #pragma unroll
    for (int j = 0; j < 16; ++j) acc[j] = 0.f;

    for (int kt = 0; kt < 32; ++kt) {
        __syncthreads();
        for (int idx = tid; idx < 64 * 32; idx += 256) {
            int d = idx >> 5, k = idx & 31;
            ks[d][k] = kp[(size_t)d * S + kt * 32 + k];
            vs[d][k] = vp[(size_t)d * S + kt * 32 + k];
        }
        __syncthreads();

        float sc[8];
        #pragma unroll
        for (int kk = 0; kk < 8; ++kk) sc[kk] = 0.f;
        #pragma unroll 4
        for (int d = 0; d < 64; ++d) {
            float qv = qs[d][q];
            #pragma unroll
            for (int kk = 0; kk < 8; ++kk) sc[kk] += qv * ks[d][kq * 8 + kk];
        }

        float tmax = sc[0];
        #pragma unroll
        for (int kk = 1; kk < 8; ++kk) tmax = fmaxf(tmax, sc[kk]);
        tmax = fmaxf(tmax, __shfl_xor(tmax, 1));
        tmax = fmaxf(tmax, __shfl_xor(tmax, 2));
        float mnew = fmaxf(m, tmax);
        float fac = expf(m - mnew);

        float tsum = 0.f;
        #pragma unroll
        for (int kk = 0; kk < 8; ++kk) {
            float p = expf(sc[kk] - mnew);
            ps[q][kq * 8 + kk] = p;
            tsum += p;
        }
        tsum += __shfl_xor(tsum, 1);
        tsum += __shfl_xor(tsum, 2);
        l = l * fac + tsum;
        m = mnew;
        #pragma unroll
        for (int j = 0; j < 16; ++j) acc[j] *= fac;
        __syncthreads();

        #pragma unroll 4
        for (int k = 0; k < 32; ++k) {
            float pv = ps[q][k];
            #pragma unroll
            for (int d16 = 0; d16 < 16; ++d16)
                acc[d16] += pv * vs[kq * 16 + d16][k];
        }
    }

    float inv = 1.f / l;
    #pragma unroll
    for (int d16 = 0; d16 < 16; ++d16)
        qp[(size_t)(kq * 16 + d16) * S + q0 + q] = acc[d16] * inv;
}

// out[b][o][s] = sum_c P[o][c]*attn[b][c][s] + pb[o] + X[b][o][s]
__global__ __launch_bounds__(256) void proj_gemm(
    const float* __restrict__ attn, const float* __restrict__ W,
    const float* __restrict__ bias, const float* __restrict__ Xres,
    float* __restrict__ out)
{
    const int tx = threadIdx.x, ty = threadIdx.y;
    const int tid = ty * 16 + tx;
    const int s0 = blockIdx.x * 64;
    const int o0 = blockIdx.y * 64;
    const int bi = blockIdx.z;

    __shared__ float Ws[16][65];
    __shared__ float Xs[16][65];

    float acc[4][4];
    #pragma unroll
    for (int i = 0; i < 4; ++i)
        #pragma unroll
        for (int j = 0; j < 4; ++j) acc[i][j] = 0.f;

    const int wk = tid & 15, wm = tid >> 4;
    const int xn = tid & 63, xk = tid >> 6;

    for (int k0 = 0; k0 < C; k0 += 16) {
        __syncthreads();
        #pragma unroll
        for (int p = 0; p < 4; ++p) {
            int mm = wm + p * 16;
            Ws[wk][mm] = W[(size_t)(o0 + mm) * C + k0 + wk];
        }
        #pragma unroll
        for (int p = 0; p < 4; ++p) {
            int k = xk + p * 4;
            Xs[k][xn] = attn[((size_t)bi * OC3 + k0 + k) * S + s0 + xn];
        }
        __syncthreads();
        #pragma unroll
        for (int kk = 0; kk < 16; ++kk) {
            float a[4], b[4];
            #pragma unroll
            for (int i = 0; i < 4; ++i) a[i] = Ws[kk][ty + 16 * i];
            #pragma unroll
            for (int j = 0; j < 4; ++j) b[j] = Xs[kk][tx + 16 * j];
            #pragma unroll
            for (int i = 0; i < 4; ++i)
                #pragma unroll
                for (int j = 0; j < 4; ++j) acc[i][j] += a[i] * b[j];
        }
    }
    #pragma unroll
    for (int i = 0; i < 4; ++i) {
        int o = o0 + ty + 16 * i;
        float bv = bias[o];
        #pragma unroll
        for (int j = 0; j < 4; ++j) {
            size_t oidx = ((size_t)bi * C + o) * S + s0 + tx + 16 * j;
            out[oidx] = acc[i][j] + bv + Xres[oidx];
        }
    }
}

extern "C" void kernel_launch(void* const* d_in, const int* in_sizes, int n_in,
                              void* d_out, int out_size, void* d_ws, size_t ws_size,
                              hipStream_t stream) {
    const float* X      = (const float*)d_in[0];
    const float* norm_w = (const float*)d_in[1];
    const float* norm_b = (const float*)d_in[2];
    const float* qkv_w  = (const float*)d_in[3];
    const float* qkv_b  = (const float*)d_in[4];
    const float* proj_w = (const float*)d_in[5];
    const float* proj_b = (const float*)d_in[6];
    float* out = (float*)d_out;

    float* ws     = (float*)d_ws;
    float* scaleA = ws;                 // 8*512
    float* shiftB = ws + 4096;          // 8*512
    float* qkv    = ws + 8192;          // 8*1536*1024 floats (q region reused as attn out)

    gn_stats<<<dim3(BATCH * GROUPS), 256, 0, stream>>>(X, norm_w, norm_b, scaleA, shiftB);
    qkv_gemm<<<dim3(S / 64, OC3 / 64, BATCH), dim3(16, 16), 0, stream>>>(
        X, qkv_w, qkv_b, scaleA, shiftB, qkv);
    attn_kernel<<<dim3(S / 64, HEADS, BATCH), 256, 0, stream>>>(qkv);
    proj_gemm<<<dim3(S / 64, C / 64, BATCH), dim3(16, 16), 0, stream>>>(
        qkv, proj_w, proj_b, X, out);
}

// Round 2
// 420.214 us; speedup vs baseline: 2.4245x; 2.4245x over previous
//
#include <hip/hip_runtime.h>
#include <hip/hip_bf16.h>

// AttentionBlock  B=8, C=512, H=W=32 (S=1024), heads=8, hd=64, groups=32
// Round 2: bf16 MFMA flash-attention (16x16x32), fp32 tiled GEMMs unchanged.

#define BATCH 8
#define C 512
#define S 1024
#define HEADS 8
#define HD 64
#define GROUPS 32
#define CPG 16
#define OC3 1536

typedef short bf16x8 __attribute__((ext_vector_type(8)));
typedef float f32x4 __attribute__((ext_vector_type(4)));

__device__ inline short f2bf(float x) {
    union { float f; unsigned u; } v; v.f = x;
    unsigned r = v.u + 0x7fffu + ((v.u >> 16) & 1u);   // RNE
    return (short)(r >> 16);
}

__global__ __launch_bounds__(256) void gn_stats(
    const float* __restrict__ X, const float* __restrict__ nw,
    const float* __restrict__ nb, float* __restrict__ scaleA,
    float* __restrict__ shiftB)
{
    const int blk = blockIdx.x;
    const int bi = blk >> 5, g = blk & 31;
    const int tid = threadIdx.x;
    const size_t base = ((size_t)bi * C + g * CPG) * S;
    float s = 0.f, ss = 0.f;
    for (int i = tid; i < CPG * S; i += 256) {
        float v = X[base + i];
        s += v; ss += v * v;
    }
    __shared__ float rs[256], rss[256];
    rs[tid] = s; rss[tid] = ss;
    __syncthreads();
    for (int off = 128; off > 0; off >>= 1) {
        if (tid < off) { rs[tid] += rs[tid + off]; rss[tid] += rss[tid + off]; }
        __syncthreads();
    }
    __shared__ float sh_mean, sh_rstd;
    if (tid == 0) {
        float mean = rs[0] * (1.f / (CPG * S));
        float var = rss[0] * (1.f / (CPG * S)) - mean * mean;
        sh_mean = mean;
        sh_rstd = rsqrtf(var + 1e-5f);
    }
    __syncthreads();
    if (tid < CPG) {
        int c = g * CPG + tid;
        float rw = sh_rstd * nw[c];
        scaleA[bi * C + c] = rw;
        shiftB[bi * C + c] = nb[c] - sh_mean * rw;
    }
}

__global__ __launch_bounds__(256) void qkv_gemm(
    const float* __restrict__ X, const float* __restrict__ W,
    const float* __restrict__ bias, const float* __restrict__ scaleA,
    const float* __restrict__ shiftB, float* __restrict__ out)
{
    const int tx = threadIdx.x, ty = threadIdx.y;
    const int tid = ty * 16 + tx;
    const int s0 = blockIdx.x * 64;
    const int o0 = blockIdx.y * 64;
    const int bi = blockIdx.z;

    __shared__ float Ws[16][65];
    __shared__ float Xs[16][65];

    float acc[4][4];
    #pragma unroll
    for (int i = 0; i < 4; ++i)
        #pragma unroll
        for (int j = 0; j < 4; ++j) acc[i][j] = 0.f;

    const int wk = tid & 15, wm = tid >> 4;
    const int xn = tid & 63, xk = tid >> 6;

    for (int k0 = 0; k0 < C; k0 += 16) {
        __syncthreads();
        #pragma unroll
        for (int p = 0; p < 4; ++p) {
            int m = wm + p * 16;
            Ws[wk][m] = W[(size_t)(o0 + m) * C + k0 + wk];
        }
        #pragma unroll
        for (int p = 0; p < 4; ++p) {
            int k = xk + p * 4;
            int c = k0 + k;
            float sa = scaleA[bi * C + c];
            float sb = shiftB[bi * C + c];
            float x = X[((size_t)bi * C + c) * S + s0 + xn];
            Xs[k][xn] = x * sa + sb;
        }
        __syncthreads();
        #pragma unroll
        for (int kk = 0; kk < 16; ++kk) {
            float a[4], b[4];
            #pragma unroll
            for (int i = 0; i < 4; ++i) a[i] = Ws[kk][ty + 16 * i];
            #pragma unroll
            for (int j = 0; j < 4; ++j) b[j] = Xs[kk][tx + 16 * j];
            #pragma unroll
            for (int i = 0; i < 4; ++i)
                #pragma unroll
                for (int j = 0; j < 4; ++j) acc[i][j] += a[i] * b[j];
        }
    }
    #pragma unroll
    for (int i = 0; i < 4; ++i) {
        int o = o0 + ty + 16 * i;
        float bv = bias[o];
        #pragma unroll
        for (int j = 0; j < 4; ++j)
            out[((size_t)bi * OC3 + o) * S + s0 + tx + 16 * j] = acc[i][j] + bv;
    }
}

// bf16 MFMA flash attention.
// grid (16 qblocks, 8 heads, 8 batch), 256 threads = 4 waves.
// Wave w owns queries [qw, qw+16). K-tiles of 64 keys staged in LDS as bf16.
// Qs/Ks transposed [s][d] (rows 72 bf16 = 144B, 16B aligned), Vs natural [d][k].
// Scores: S[q][k] = mfma(A=Q^T, B=K). PV: O[d][q] = mfma(A=V, B=P^T).
__global__ __launch_bounds__(256) void attn_mfma(float* __restrict__ qkv)
{
    const int qb = blockIdx.x, h = blockIdx.y, bi = blockIdx.z;
    const int tid = threadIdx.x;
    const int wave = tid >> 6, lane = tid & 63;
    const int lr = lane & 15, lg = lane >> 4;
    const int q0 = qb * 64;
    const int qw = wave * 16;

    float* qp = qkv + ((size_t)bi * OC3 + h * HD) * S;
    const float* kp = qkv + ((size_t)bi * OC3 + C + h * HD) * S;
    const float* vp = qkv + ((size_t)bi * OC3 + 2 * C + h * HD) * S;

    __shared__ short Qs[64][72];   // [q][d]  (transposed, scaled)
    __shared__ short Ks[64][72];   // [k][d]  (transposed)
    __shared__ short Vs[64][72];   // [d][k]  (natural)
    __shared__ short Ps[64][72];   // [q][k]
    __shared__ float Fs[4][16];    // per-wave rescale factor by q-col
    __shared__ float Ls[4][16];    // per-wave denom by q-col

    // ---- stage Q^T (scaled) ----
    #pragma unroll
    for (int p = 0; p < 2; ++p) {
        int idx = p * 256 + tid;
        int q = idx & 63, dc = idx >> 6;            // dc 0..7
        bf16x8 frag;
        #pragma unroll
        for (int j = 0; j < 8; ++j)
            frag[j] = f2bf(qp[(size_t)(dc * 8 + j) * S + q0 + q] * 0.125f);
        *(bf16x8*)&Qs[q][dc * 8] = frag;
    }
    __syncthreads();

    // hoist Q fragments (A operand: A[q][d], row=lr -> q, chunk 8*lg)
    bf16x8 aq0 = *(bf16x8*)&Qs[qw + lr][lg * 8];
    bf16x8 aq1 = *(bf16x8*)&Qs[qw + lr][32 + lg * 8];

    float mrun[4], lrun[4];
    #pragma unroll
    for (int i = 0; i < 4; ++i) { mrun[i] = -1e30f; lrun[i] = 0.f; }
    f32x4 acc_o[4];
    #pragma unroll
    for (int df = 0; df < 4; ++df) acc_o[df] = (f32x4){0.f, 0.f, 0.f, 0.f};

    for (int kt = 0; kt < 16; ++kt) {
        const int kk0 = kt * 64;
        __syncthreads();   // previous tile's LDS reads done

        // ---- stage K transposed: Ks[k][d] ----
        #pragma unroll
        for (int p = 0; p < 2; ++p) {
            int idx = p * 256 + tid;
            int k = idx & 63, dc = idx >> 6;        // per wave: k=lane (coalesced)
            bf16x8 frag;
            #pragma unroll
            for (int j = 0; j < 8; ++j)
                frag[j] = f2bf(kp[(size_t)(dc * 8 + j) * S + kk0 + k]);
            *(bf16x8*)&Ks[k][dc * 8] = frag;
        }
        // ---- stage V natural: Vs[d][k] ----
        #pragma unroll
        for (int p = 0; p < 2; ++p) {
            int idx = p * 256 + tid;
            int d = idx >> 3, kc = idx & 7;
            f32x4 a = *(const f32x4*)(vp + (size_t)d * S + kk0 + kc * 8);
            f32x4 b = *(const f32x4*)(vp + (size_t)d * S + kk0 + kc * 8 + 4);
            bf16x8 frag;
            #pragma unroll
            for (int j = 0; j < 4; ++j) { frag[j] = f2bf(a[j]); frag[4 + j] = f2bf(b[j]); }
            *(bf16x8*)&Vs[d][kc * 8] = frag;
        }
        __syncthreads();

        // ---- scores: 16q x 64k strip per wave ----
        f32x4 sc[4];
        #pragma unroll
        for (int kf = 0; kf < 4; ++kf) {
            bf16x8 b0 = *(bf16x8*)&Ks[kf * 16 + lr][lg * 8];
            bf16x8 b1 = *(bf16x8*)&Ks[kf * 16 + lr][32 + lg * 8];
            f32x4 z = (f32x4){0.f, 0.f, 0.f, 0.f};
            z = __builtin_amdgcn_mfma_f32_16x16x32_bf16(aq0, b0, z, 0, 0, 0);
            sc[kf] = __builtin_amdgcn_mfma_f32_16x16x32_bf16(aq1, b1, z, 0, 0, 0);
        }

        // ---- online softmax (row q = qw + 4*lg + i, col k = kf*16 + lr) ----
        float mx[4];
        #pragma unroll
        for (int i = 0; i < 4; ++i)
            mx[i] = fmaxf(fmaxf(sc[0][i], sc[1][i]), fmaxf(sc[2][i], sc[3][i]));
        #pragma unroll
        for (int m = 1; m <= 8; m <<= 1)
            #pragma unroll
            for (int i = 0; i < 4; ++i)
                mx[i] = fmaxf(mx[i], __shfl_xor(mx[i], m));

        float fac[4];
        #pragma unroll
        for (int i = 0; i < 4; ++i) {
            float mnew = fmaxf(mrun[i], mx[i]);
            fac[i] = __expf(mrun[i] - mnew);
            mrun[i] = mnew;
        }
        float sum[4] = {0.f, 0.f, 0.f, 0.f};
        #pragma unroll
        for (int kf = 0; kf < 4; ++kf) {
            #pragma unroll
            for (int i = 0; i < 4; ++i) {
                float pp = __expf(sc[kf][i] - mrun[i]);
                sum[i] += pp;
                float po = __shfl_xor(pp, 1);
                if (!(lr & 1)) {
                    unsigned pk = (unsigned)(unsigned short)f2bf(pp)
                                | ((unsigned)(unsigned short)f2bf(po) << 16);
                    *(unsigned*)&Ps[qw + 4 * lg + i][kf * 16 + lr] = pk;
                }
            }
        }
        #pragma unroll
        for (int m = 1; m <= 8; m <<= 1)
            #pragma unroll
            for (int i = 0; i < 4; ++i)
                sum[i] += __shfl_xor(sum[i], m);
        #pragma unroll
        for (int i = 0; i < 4; ++i)
            lrun[i] = lrun[i] * fac[i] + sum[i];
        if (lr == 0) {
            #pragma unroll
            for (int i = 0; i < 4; ++i) Fs[wave][4 * lg + i] = fac[i];
        }
        __syncthreads();

        // ---- rescale + PV ----
        float fc = Fs[wave][lr];
        #pragma unroll
        for (int df = 0; df < 4; ++df) acc_o[df] *= fc;

        bf16x8 pb0 = *(bf16x8*)&Ps[qw + lr][lg * 8];
        bf16x8 pb1 = *(bf16x8*)&Ps[qw + lr][32 + lg * 8];
        #pragma unroll
        for (int df = 0; df < 4; ++df) {
            bf16x8 v0 = *(bf16x8*)&Vs[df * 16 + lr][lg * 8];
            bf16x8 v1 = *(bf16x8*)&Vs[df * 16 + lr][32 + lg * 8];
            acc_o[df] = __builtin_amdgcn_mfma_f32_16x16x32_bf16(v0, pb0, acc_o[df], 0, 0, 0);
            acc_o[df] = __builtin_amdgcn_mfma_f32_16x16x32_bf16(v1, pb1, acc_o[df], 0, 0, 0);
        }
    }

    if (lr == 0) {
        #pragma unroll
        for (int i = 0; i < 4; ++i) Ls[wave][4 * lg + i] = lrun[i];
    }
    __syncthreads();
    float linv = 1.f / Ls[wave][lr];
    #pragma unroll
    for (int df = 0; df < 4; ++df)
        #pragma unroll
        for (int i = 0; i < 4; ++i)
            qp[(size_t)(df * 16 + 4 * lg + i) * S + q0 + qw + lr] = acc_o[df][i] * linv;
}

__global__ __launch_bounds__(256) void proj_gemm(
    const float* __restrict__ attn, const float* __restrict__ W,
    const float* __restrict__ bias, const float* __restrict__ Xres,
    float* __restrict__ out)
{
    const int tx = threadIdx.x, ty = threadIdx.y;
    const int tid = ty * 16 + tx;
    const int s0 = blockIdx.x * 64;
    const int o0 = blockIdx.y * 64;
    const int bi = blockIdx.z;

    __shared__ float Ws[16][65];
    __shared__ float Xs[16][65];

    float acc[4][4];
    #pragma unroll
    for (int i = 0; i < 4; ++i)
        #pragma unroll
        for (int j = 0; j < 4; ++j) acc[i][j] = 0.f;

    const int wk = tid & 15, wm = tid >> 4;
    const int xn = tid & 63, xk = tid >> 6;

    for (int k0 = 0; k0 < C; k0 += 16) {
        __syncthreads();
        #pragma unroll
        for (int p = 0; p < 4; ++p) {
            int mm = wm + p * 16;
            Ws[wk][mm] = W[(size_t)(o0 + mm) * C + k0 + wk];
        }
        #pragma unroll
        for (int p = 0; p < 4; ++p) {
            int k = xk + p * 4;
            Xs[k][xn] = attn[((size_t)bi * OC3 + k0 + k) * S + s0 + xn];
        }
        __syncthreads();
        #pragma unroll
        for (int kk = 0; kk < 16; ++kk) {
            float a[4], b[4];
            #pragma unroll
            for (int i = 0; i < 4; ++i) a[i] = Ws[kk][ty + 16 * i];
            #pragma unroll
            for (int j = 0; j < 4; ++j) b[j] = Xs[kk][tx + 16 * j];
            #pragma unroll
            for (int i = 0; i < 4; ++i)
                #pragma unroll
                for (int j = 0; j < 4; ++j) acc[i][j] += a[i] * b[j];
        }
    }
    #pragma unroll
    for (int i = 0; i < 4; ++i) {
        int o = o0 + ty + 16 * i;
        float bv = bias[o];
        #pragma unroll
        for (int j = 0; j < 4; ++j) {
            size_t oidx = ((size_t)bi * C + o) * S + s0 + tx + 16 * j;
            out[oidx] = acc[i][j] + bv + Xres[oidx];
        }
    }
}

extern "C" void kernel_launch(void* const* d_in, const int* in_sizes, int n_in,
                              void* d_out, int out_size, void* d_ws, size_t ws_size,
                              hipStream_t stream) {
    const float* X      = (const float*)d_in[0];
    const float* norm_w = (const float*)d_in[1];
    const float* norm_b = (const float*)d_in[2];
    const float* qkv_w  = (const float*)d_in[3];
    const float* qkv_b  = (const float*)d_in[4];
    const float* proj_w = (const float*)d_in[5];
    const float* proj_b = (const float*)d_in[6];
    float* out = (float*)d_out;

    float* ws     = (float*)d_ws;
    float* scaleA = ws;                 // 8*512
    float* shiftB = ws + 4096;          // 8*512
    float* qkv    = ws + 8192;          // 8*1536*1024 floats

    gn_stats<<<dim3(BATCH * GROUPS), 256, 0, stream>>>(X, norm_w, norm_b, scaleA, shiftB);
    qkv_gemm<<<dim3(S / 64, OC3 / 64, BATCH), dim3(16, 16), 0, stream>>>(
        X, qkv_w, qkv_b, scaleA, shiftB, qkv);
    attn_mfma<<<dim3(S / 64, HEADS, BATCH), 256, 0, stream>>>(qkv);
    proj_gemm<<<dim3(S / 64, C / 64, BATCH), dim3(16, 16), 0, stream>>>(
        qkv, proj_w, proj_b, X, out);
}

// Round 3
// 223.921 us; speedup vs baseline: 4.5499x; 1.8766x over previous
//
#include <hip/hip_runtime.h>
#include <hip/hip_bf16.h>

// AttentionBlock  B=8, C=512, H=W=32 (S=1024), heads=8, hd=64, groups=32
// Round 3: full bf16 MFMA pipeline.
//   gn_stats -> wconv(x2) -> xnt (GN-affine + transpose to [s][c] bf16)
//   qkv_mfma (128x128 tile, global_load_lds, frag-ordered LDS) -> Qt/Kt [s][d], V [d][s]
//   attn_mfma (barrier-free, direct global frags, P-only LDS) -> attn_t [s][c]
//   proj_mfma (+bias+residual, fp32 out)

#define BATCH 8
#define C 512
#define S 1024
#define HEADS 8
#define OC3 1536

typedef short bf16x8 __attribute__((ext_vector_type(8)));
typedef float f32x4 __attribute__((ext_vector_type(4)));
typedef unsigned short u16;
typedef unsigned short u16x4 __attribute__((ext_vector_type(4)));

__device__ inline short f2bf(float x) {
    union { float f; unsigned u; } v; v.f = x;
    unsigned r = v.u + 0x7fffu + ((v.u >> 16) & 1u);   // RNE
    return (short)(r >> 16);
}

__device__ inline void gload_lds16(const u16* g, short* l) {
    __builtin_amdgcn_global_load_lds(
        (const __attribute__((address_space(1))) unsigned int*)g,
        (__attribute__((address_space(3))) unsigned int*)l, 16, 0, 0);
}

__global__ __launch_bounds__(256) void gn_stats(
    const float* __restrict__ X, const float* __restrict__ nw,
    const float* __restrict__ nb, float* __restrict__ scaleA,
    float* __restrict__ shiftB)
{
    const int blk = blockIdx.x;
    const int bi = blk >> 5, g = blk & 31;
    const int tid = threadIdx.x;
    const size_t base = ((size_t)bi * C + g * 16) * S;     // 16 ch/group * 1024
    float s = 0.f, ss = 0.f;
    for (int i = tid; i < 16 * S; i += 256) {
        float v = X[base + i];
        s += v; ss += v * v;
    }
    __shared__ float rs[256], rss[256];
    rs[tid] = s; rss[tid] = ss;
    __syncthreads();
    for (int off = 128; off > 0; off >>= 1) {
        if (tid < off) { rs[tid] += rs[tid + off]; rss[tid] += rss[tid + off]; }
        __syncthreads();
    }
    __shared__ float sh_mean, sh_rstd;
    if (tid == 0) {
        float mean = rs[0] * (1.f / (16 * S));
        float var = rss[0] * (1.f / (16 * S)) - mean * mean;
        sh_mean = mean;
        sh_rstd = rsqrtf(var + 1e-5f);
    }
    __syncthreads();
    if (tid < 16) {
        int c = g * 16 + tid;
        float rw = sh_rstd * nw[c];
        scaleA[bi * C + c] = rw;
        shiftB[bi * C + c] = nb[c] - sh_mean * rw;
    }
}

__global__ __launch_bounds__(256) void wconv(
    const float* __restrict__ w, u16* __restrict__ o, int n8)
{
    int i = blockIdx.x * 256 + threadIdx.x;
    if (i < n8) {
        f32x4 a = *(const f32x4*)(w + (size_t)i * 8);
        f32x4 b = *(const f32x4*)(w + (size_t)i * 8 + 4);
        bf16x8 r;
        #pragma unroll
        for (int j = 0; j < 4; ++j) { r[j] = f2bf(a[j]); r[4 + j] = f2bf(b[j]); }
        *(bf16x8*)(o + (size_t)i * 8) = r;
    }
}

// Xn_t[b][s][c] = bf16(X[b][c][s]*scaleA + shiftB). Tile 64c x 64s.
__global__ __launch_bounds__(256) void xnt_kernel(
    const float* __restrict__ X, const float* __restrict__ scaleA,
    const float* __restrict__ shiftB, u16* __restrict__ Xn_t)
{
    const int s0 = blockIdx.x * 64, c0 = blockIdx.y * 64, bi = blockIdx.z;
    const int tid = threadIdx.x;
    __shared__ float T[64][65];
    #pragma unroll
    for (int p = 0; p < 4; ++p) {
        int c = p * 16 + (tid >> 4);
        int sl = (tid & 15) * 4;
        float sa = scaleA[bi * C + c0 + c];
        float sb = shiftB[bi * C + c0 + c];
        f32x4 v = *(const f32x4*)(X + ((size_t)bi * C + c0 + c) * S + s0 + sl);
        #pragma unroll
        for (int j = 0; j < 4; ++j) T[c][sl + j] = v[j] * sa + sb;
    }
    __syncthreads();
    #pragma unroll
    for (int p = 0; p < 2; ++p) {
        int s = p * 32 + (tid >> 3);
        int cc = tid & 7;
        bf16x8 o;
        #pragma unroll
        for (int j = 0; j < 8; ++j) o[j] = f2bf(T[cc * 8 + j][s]);
        *(bf16x8*)(Xn_t + (size_t)bi * S * C + (size_t)(s0 + s) * C + c0 + cc * 8) = o;
    }
}

// GEMM: A[M][K] bf16 x Bt[N][K] bf16 -> per-batch.
// 128x128 tile, BK=32, 4 waves (2x2), frag-ordered LDS via global_load_lds.
// Epilogue: Q/K regions -> transposed [s][d] bf16; V region -> [d][s] bf16.
__global__ __launch_bounds__(256) void qkv_mfma(
    const u16* __restrict__ A, const u16* __restrict__ Bt,
    const float* __restrict__ bias,
    u16* __restrict__ Qt, u16* __restrict__ Kt, u16* __restrict__ Vn)
{
    const int n0 = blockIdx.x * 128, m0 = blockIdx.y * 128;
    const int bi = blockIdx.z;
    const int tid = threadIdx.x, wave = tid >> 6, lane = tid & 63;
    const int lr = lane & 15, lg = lane >> 4;
    const int wr = wave >> 1, wc = wave & 1;

    __shared__ __attribute__((aligned(16))) short As[8][512];
    __shared__ __attribute__((aligned(16))) short Bs[8][512];

    f32x4 acc[4][4];
    #pragma unroll
    for (int i = 0; i < 4; ++i)
        #pragma unroll
        for (int j = 0; j < 4; ++j) acc[i][j] = (f32x4){0.f, 0.f, 0.f, 0.f};

    const u16* aP0 = A + (size_t)(m0 + wave * 16 + lr) * C + lg * 8;
    const u16* aP1 = A + (size_t)(m0 + (wave + 4) * 16 + lr) * C + lg * 8;
    const u16* bP0 = Bt + (size_t)bi * S * C + (size_t)(n0 + wave * 16 + lr) * C + lg * 8;
    const u16* bP1 = Bt + (size_t)bi * S * C + (size_t)(n0 + (wave + 4) * 16 + lr) * C + lg * 8;

    for (int k0 = 0; k0 < C; k0 += 32) {
        gload_lds16(aP0 + k0, &As[wave][0]);
        gload_lds16(aP1 + k0, &As[wave + 4][0]);
        gload_lds16(bP0 + k0, &Bs[wave][0]);
        gload_lds16(bP1 + k0, &Bs[wave + 4][0]);
        __syncthreads();
        bf16x8 af[4], bfr[4];
        #pragma unroll
        for (int mf = 0; mf < 4; ++mf) af[mf] = *(bf16x8*)&As[wr * 4 + mf][lane * 8];
        #pragma unroll
        for (int nf = 0; nf < 4; ++nf) bfr[nf] = *(bf16x8*)&Bs[wc * 4 + nf][lane * 8];
        #pragma unroll
        for (int mf = 0; mf < 4; ++mf)
            #pragma unroll
            for (int nf = 0; nf < 4; ++nf)
                acc[mf][nf] = __builtin_amdgcn_mfma_f32_16x16x32_bf16(
                    af[mf], bfr[nf], acc[mf][nf], 0, 0, 0);
        __syncthreads();
    }

    #pragma unroll
    for (int mf = 0; mf < 4; ++mf) {
        const int o3b = m0 + wr * 64 + mf * 16 + 4 * lg;   // rows o3b..o3b+3
        float bv[4];
        #pragma unroll
        for (int i = 0; i < 4; ++i) bv[i] = bias[o3b + i];
        #pragma unroll
        for (int nf = 0; nf < 4; ++nf) {
            const int s = n0 + wc * 64 + nf * 16 + lr;
            if (m0 < 512) {          // Q -> Qt[b][h][s][d]
                int h = o3b >> 6, d = o3b & 63;
                u16x4 pk;
                #pragma unroll
                for (int i = 0; i < 4; ++i) pk[i] = (u16)f2bf(acc[mf][nf][i] + bv[i]);
                *(u16x4*)(Qt + (((size_t)bi * 8 + h) * S + s) * 64 + d) = pk;
            } else if (m0 < 1024) {  // K -> Kt[b][h][s][d]
                int ok = o3b - 512;
                int h = ok >> 6, d = ok & 63;
                u16x4 pk;
                #pragma unroll
                for (int i = 0; i < 4; ++i) pk[i] = (u16)f2bf(acc[mf][nf][i] + bv[i]);
                *(u16x4*)(Kt + (((size_t)bi * 8 + h) * S + s) * 64 + d) = pk;
            } else {                 // V -> Vn[b][c][s]
                int ov = o3b - 1024;
                #pragma unroll
                for (int i = 0; i < 4; ++i)
                    Vn[(size_t)(bi * C + ov + i) * S + s] = (u16)f2bf(acc[mf][nf][i] + bv[i]);
            }
        }
    }
}

// Attention: barrier-free, per-wave 16 queries. Q/K/V frags direct from global.
// Only P goes through LDS (frag-ordered, per-wave private).
__global__ __launch_bounds__(256) void attn_mfma(
    const u16* __restrict__ Qt, const u16* __restrict__ Kt,
    const u16* __restrict__ Vn, u16* __restrict__ At)
{
    const int qb = blockIdx.x, h = blockIdx.y, bi = blockIdx.z;
    const int tid = threadIdx.x, wave = tid >> 6, lane = tid & 63;
    const int lr = lane & 15, lg = lane >> 4;
    const int q0 = qb * 64 + wave * 16;

    const u16* qt = Qt + ((size_t)bi * 8 + h) * S * 64;
    const u16* kt = Kt + ((size_t)bi * 8 + h) * S * 64;
    const u16* vn = Vn + (size_t)(bi * C + h * 64) * S;

    __shared__ __attribute__((aligned(16))) short Pf[4][2][64][8];

    bf16x8 aq0 = *(const bf16x8*)(qt + (size_t)(q0 + lr) * 64 + lg * 8);
    bf16x8 aq1 = *(const bf16x8*)(qt + (size_t)(q0 + lr) * 64 + 32 + lg * 8);

    float mrun[4], lrun[4];
    #pragma unroll
    for (int i = 0; i < 4; ++i) { mrun[i] = -1e30f; lrun[i] = 0.f; }
    f32x4 acc[4];   // O[q=4lg+i][d=nf*16+lr]
    #pragma unroll
    for (int nf = 0; nf < 4; ++nf) acc[nf] = (f32x4){0.f, 0.f, 0.f, 0.f};

    for (int kt0 = 0; kt0 < S; kt0 += 64) {
        // ---- scores: 16q x 64k ----
        f32x4 sc[4];
        #pragma unroll
        for (int kf = 0; kf < 4; ++kf) {
            bf16x8 b0 = *(const bf16x8*)(kt + (size_t)(kt0 + kf * 16 + lr) * 64 + lg * 8);
            bf16x8 b1 = *(const bf16x8*)(kt + (size_t)(kt0 + kf * 16 + lr) * 64 + 32 + lg * 8);
            f32x4 z = (f32x4){0.f, 0.f, 0.f, 0.f};
            z = __builtin_amdgcn_mfma_f32_16x16x32_bf16(aq0, b0, z, 0, 0, 0);
            sc[kf] = __builtin_amdgcn_mfma_f32_16x16x32_bf16(aq1, b1, z, 0, 0, 0);
        }
        #pragma unroll
        for (int kf = 0; kf < 4; ++kf) sc[kf] = sc[kf] * 0.125f;

        // ---- online softmax ----
        float mx[4];
        #pragma unroll
        for (int i = 0; i < 4; ++i)
            mx[i] = fmaxf(fmaxf(sc[0][i], sc[1][i]), fmaxf(sc[2][i], sc[3][i]));
        #pragma unroll
        for (int m = 1; m <= 8; m <<= 1)
            #pragma unroll
            for (int i = 0; i < 4; ++i)
                mx[i] = fmaxf(mx[i], __shfl_xor(mx[i], m));
        float fac[4];
        #pragma unroll
        for (int i = 0; i < 4; ++i) {
            float mnew = fmaxf(mrun[i], mx[i]);
            fac[i] = __expf(mrun[i] - mnew);
            mrun[i] = mnew;
        }
        float sum[4] = {0.f, 0.f, 0.f, 0.f};
        #pragma unroll
        for (int kf = 0; kf < 4; ++kf) {
            #pragma unroll
            for (int i = 0; i < 4; ++i) {
                float pp = __expf(sc[kf][i] - mrun[i]);
                sum[i] += pp;
                float po = __shfl_xor(pp, 1);
                if (!(lr & 1)) {
                    unsigned pk = (unsigned)(u16)f2bf(pp)
                                | ((unsigned)(u16)f2bf(po) << 16);
                    int lanep = (4 * lg + i) + 16 * ((kf & 1) * 2 + (lr >> 3));
                    *(unsigned*)&Pf[wave][kf >> 1][lanep][lr & 7] = pk;
                }
            }
        }
        #pragma unroll
        for (int m = 1; m <= 8; m <<= 1)
            #pragma unroll
            for (int i = 0; i < 4; ++i)
                sum[i] += __shfl_xor(sum[i], m);
        f32x4 ffac;
        #pragma unroll
        for (int i = 0; i < 4; ++i) {
            lrun[i] = lrun[i] * fac[i] + sum[i];
            ffac[i] = fac[i];
        }
        #pragma unroll
        for (int nf = 0; nf < 4; ++nf) acc[nf] *= ffac;

        // ---- PV ----
        bf16x8 pa0 = *(bf16x8*)&Pf[wave][0][lane][0];
        bf16x8 pa1 = *(bf16x8*)&Pf[wave][1][lane][0];
        #pragma unroll
        for (int nf = 0; nf < 4; ++nf) {
            bf16x8 v0 = *(const bf16x8*)(vn + (size_t)(nf * 16 + lr) * S + kt0 + lg * 8);
            bf16x8 v1 = *(const bf16x8*)(vn + (size_t)(nf * 16 + lr) * S + kt0 + 32 + lg * 8);
            acc[nf] = __builtin_amdgcn_mfma_f32_16x16x32_bf16(pa0, v0, acc[nf], 0, 0, 0);
            acc[nf] = __builtin_amdgcn_mfma_f32_16x16x32_bf16(pa1, v1, acc[nf], 0, 0, 0);
        }
    }

    float linv[4];
    #pragma unroll
    for (int i = 0; i < 4; ++i) linv[i] = 1.f / lrun[i];
    #pragma unroll
    for (int nf = 0; nf < 4; ++nf)
        #pragma unroll
        for (int i = 0; i < 4; ++i)
            At[((size_t)bi * S + q0 + 4 * lg + i) * C + h * 64 + nf * 16 + lr] =
                (u16)f2bf(acc[nf][i] * linv[i]);
}

// proj: A=Wp[512][512] x Bt=attn_t[s][c] + bias + residual -> fp32 out
__global__ __launch_bounds__(256) void proj_mfma(
    const u16* __restrict__ A, const u16* __restrict__ Bt,
    const float* __restrict__ bias, const float* __restrict__ Xres,
    float* __restrict__ out)
{
    const int n0 = blockIdx.x * 128, m0 = blockIdx.y * 128;
    const int bi = blockIdx.z;
    const int tid = threadIdx.x, wave = tid >> 6, lane = tid & 63;
    const int lr = lane & 15, lg = lane >> 4;
    const int wr = wave >> 1, wc = wave & 1;

    __shared__ __attribute__((aligned(16))) short As[8][512];
    __shared__ __attribute__((aligned(16))) short Bs[8][512];

    f32x4 acc[4][4];
    #pragma unroll
    for (int i = 0; i < 4; ++i)
        #pragma unroll
        for (int j = 0; j < 4; ++j) acc[i][j] = (f32x4){0.f, 0.f, 0.f, 0.f};

    const u16* aP0 = A + (size_t)(m0 + wave * 16 + lr) * C + lg * 8;
    const u16* aP1 = A + (size_t)(m0 + (wave + 4) * 16 + lr) * C + lg * 8;
    const u16* bP0 = Bt + (size_t)bi * S * C + (size_t)(n0 + wave * 16 + lr) * C + lg * 8;
    const u16* bP1 = Bt + (size_t)bi * S * C + (size_t)(n0 + (wave + 4) * 16 + lr) * C + lg * 8;

    for (int k0 = 0; k0 < C; k0 += 32) {
        gload_lds16(aP0 + k0, &As[wave][0]);
        gload_lds16(aP1 + k0, &As[wave + 4][0]);
        gload_lds16(bP0 + k0, &Bs[wave][0]);
        gload_lds16(bP1 + k0, &Bs[wave + 4][0]);
        __syncthreads();
        bf16x8 af[4], bfr[4];
        #pragma unroll
        for (int mf = 0; mf < 4; ++mf) af[mf] = *(bf16x8*)&As[wr * 4 + mf][lane * 8];
        #pragma unroll
        for (int nf = 0; nf < 4; ++nf) bfr[nf] = *(bf16x8*)&Bs[wc * 4 + nf][lane * 8];
        #pragma unroll
        for (int mf = 0; mf < 4; ++mf)
            #pragma unroll
            for (int nf = 0; nf < 4; ++nf)
                acc[mf][nf] = __builtin_amdgcn_mfma_f32_16x16x32_bf16(
                    af[mf], bfr[nf], acc[mf][nf], 0, 0, 0);
        __syncthreads();
    }

    #pragma unroll
    for (int mf = 0; mf < 4; ++mf) {
        const int ob = m0 + wr * 64 + mf * 16 + 4 * lg;
        float bv[4];
        #pragma unroll
        for (int i = 0; i < 4; ++i) bv[i] = bias[ob + i];
        #pragma unroll
        for (int nf = 0; nf < 4; ++nf) {
            const int s = n0 + wc * 64 + nf * 16 + lr;
            #pragma unroll
            for (int i = 0; i < 4; ++i) {
                size_t oi = ((size_t)bi * C + ob + i) * S + s;
                out[oi] = acc[mf][nf][i] + bv[i] + Xres[oi];
            }
        }
    }
}

extern "C" void kernel_launch(void* const* d_in, const int* in_sizes, int n_in,
                              void* d_out, int out_size, void* d_ws, size_t ws_size,
                              hipStream_t stream) {
    const float* X      = (const float*)d_in[0];
    const float* norm_w = (const float*)d_in[1];
    const float* norm_b = (const float*)d_in[2];
    const float* qkv_w  = (const float*)d_in[3];
    const float* qkv_b  = (const float*)d_in[4];
    const float* proj_w = (const float*)d_in[5];
    const float* proj_b = (const float*)d_in[6];
    float* out = (float*)d_out;

    float* scaleA = (float*)d_ws;              // 4096 f
    float* shiftB = scaleA + 4096;             // 4096 f
    u16* Wq_bf = (u16*)(shiftB + 4096);        // 1536*512
    u16* Wp_bf = Wq_bf + 786432;               // 512*512
    u16* Xn_t  = Wp_bf + 262144;               // 8*1024*512
    u16* Qt    = Xn_t + 4194304;               // 8*8*1024*64
    u16* Kt    = Qt + 4194304;
    u16* Vn    = Kt + 4194304;                 // 8*512*1024
    u16* At    = Vn + 4194304;                 // 8*1024*512

    gn_stats<<<dim3(BATCH * 32), 256, 0, stream>>>(X, norm_w, norm_b, scaleA, shiftB);
    wconv<<<dim3(384), 256, 0, stream>>>(qkv_w, Wq_bf, 98304);
    wconv<<<dim3(128), 256, 0, stream>>>(proj_w, Wp_bf, 32768);
    xnt_kernel<<<dim3(S / 64, C / 64, BATCH), 256, 0, stream>>>(X, scaleA, shiftB, Xn_t);
    qkv_mfma<<<dim3(S / 128, OC3 / 128, BATCH), 256, 0, stream>>>(
        Wq_bf, Xn_t, qkv_b, Qt, Kt, Vn);
    attn_mfma<<<dim3(S / 64, HEADS, BATCH), 256, 0, stream>>>(Qt, Kt, Vn, At);
    proj_mfma<<<dim3(S / 128, C / 128, BATCH), 256, 0, stream>>>(
        Wp_bf, At, proj_b, X, out);
}

// Round 4
// 158.291 us; speedup vs baseline: 6.4364x; 1.4146x over previous
//
#include <hip/hip_runtime.h>
#include <hip/hip_bf16.h>

// AttentionBlock  B=8, C=512, H=W=32 (S=1024), heads=8, hd=64, groups=32
// Round 4: attn rework — double-buffered global_load_lds K/V staging with
// XOR-swizzle (pre-swizzled source, swizzled read), XCD-local grid (bh fast),
// 1/8 scale folded into Q epilogue. GEMMs unchanged from round 3.

#define BATCH 8
#define C 512
#define S 1024
#define HEADS 8
#define OC3 1536

typedef short bf16x8 __attribute__((ext_vector_type(8)));
typedef float f32x4 __attribute__((ext_vector_type(4)));
typedef unsigned short u16;
typedef unsigned short u16x4 __attribute__((ext_vector_type(4)));

__device__ inline short f2bf(float x) {
    union { float f; unsigned u; } v; v.f = x;
    unsigned r = v.u + 0x7fffu + ((v.u >> 16) & 1u);   // RNE
    return (short)(r >> 16);
}

__device__ inline void gload_lds16(const u16* g, short* l) {
    __builtin_amdgcn_global_load_lds(
        (const __attribute__((address_space(1))) unsigned int*)g,
        (__attribute__((address_space(3))) unsigned int*)l, 16, 0, 0);
}

__global__ __launch_bounds__(256) void gn_stats(
    const float* __restrict__ X, const float* __restrict__ nw,
    const float* __restrict__ nb, float* __restrict__ scaleA,
    float* __restrict__ shiftB)
{
    const int blk = blockIdx.x;
    const int bi = blk >> 5, g = blk & 31;
    const int tid = threadIdx.x;
    const size_t base = ((size_t)bi * C + g * 16) * S;
    float s = 0.f, ss = 0.f;
    for (int i = tid; i < 16 * S; i += 256) {
        float v = X[base + i];
        s += v; ss += v * v;
    }
    __shared__ float rs[256], rss[256];
    rs[tid] = s; rss[tid] = ss;
    __syncthreads();
    for (int off = 128; off > 0; off >>= 1) {
        if (tid < off) { rs[tid] += rs[tid + off]; rss[tid] += rss[tid + off]; }
        __syncthreads();
    }
    __shared__ float sh_mean, sh_rstd;
    if (tid == 0) {
        float mean = rs[0] * (1.f / (16 * S));
        float var = rss[0] * (1.f / (16 * S)) - mean * mean;
        sh_mean = mean;
        sh_rstd = rsqrtf(var + 1e-5f);
    }
    __syncthreads();
    if (tid < 16) {
        int c = g * 16 + tid;
        float rw = sh_rstd * nw[c];
        scaleA[bi * C + c] = rw;
        shiftB[bi * C + c] = nb[c] - sh_mean * rw;
    }
}

__global__ __launch_bounds__(256) void wconv(
    const float* __restrict__ w, u16* __restrict__ o, int n8)
{
    int i = blockIdx.x * 256 + threadIdx.x;
    if (i < n8) {
        f32x4 a = *(const f32x4*)(w + (size_t)i * 8);
        f32x4 b = *(const f32x4*)(w + (size_t)i * 8 + 4);
        bf16x8 r;
        #pragma unroll
        for (int j = 0; j < 4; ++j) { r[j] = f2bf(a[j]); r[4 + j] = f2bf(b[j]); }
        *(bf16x8*)(o + (size_t)i * 8) = r;
    }
}

// Xn_t[b][s][c] = bf16(X[b][c][s]*scaleA + shiftB). Tile 64c x 64s.
__global__ __launch_bounds__(256) void xnt_kernel(
    const float* __restrict__ X, const float* __restrict__ scaleA,
    const float* __restrict__ shiftB, u16* __restrict__ Xn_t)
{
    const int s0 = blockIdx.x * 64, c0 = blockIdx.y * 64, bi = blockIdx.z;
    const int tid = threadIdx.x;
    __shared__ float T[64][65];
    #pragma unroll
    for (int p = 0; p < 4; ++p) {
        int c = p * 16 + (tid >> 4);
        int sl = (tid & 15) * 4;
        float sa = scaleA[bi * C + c0 + c];
        float sb = shiftB[bi * C + c0 + c];
        f32x4 v = *(const f32x4*)(X + ((size_t)bi * C + c0 + c) * S + s0 + sl);
        #pragma unroll
        for (int j = 0; j < 4; ++j) T[c][sl + j] = v[j] * sa + sb;
    }
    __syncthreads();
    #pragma unroll
    for (int p = 0; p < 2; ++p) {
        int s = p * 32 + (tid >> 3);
        int cc = tid & 7;
        bf16x8 o;
        #pragma unroll
        for (int j = 0; j < 8; ++j) o[j] = f2bf(T[cc * 8 + j][s]);
        *(bf16x8*)(Xn_t + (size_t)bi * S * C + (size_t)(s0 + s) * C + c0 + cc * 8) = o;
    }
}

// GEMM: A[M][K] bf16 x Bt[N][K] bf16. 128x128 tile, BK=32, 4 waves.
// Q region epilogue folds the 1/8 attention scale (exact pow2).
__global__ __launch_bounds__(256) void qkv_mfma(
    const u16* __restrict__ A, const u16* __restrict__ Bt,
    const float* __restrict__ bias,
    u16* __restrict__ Qt, u16* __restrict__ Kt, u16* __restrict__ Vn)
{
    const int n0 = blockIdx.x * 128, m0 = blockIdx.y * 128;
    const int bi = blockIdx.z;
    const int tid = threadIdx.x, wave = tid >> 6, lane = tid & 63;
    const int lr = lane & 15, lg = lane >> 4;
    const int wr = wave >> 1, wc = wave & 1;

    __shared__ __attribute__((aligned(16))) short As[8][512];
    __shared__ __attribute__((aligned(16))) short Bs[8][512];

    f32x4 acc[4][4];
    #pragma unroll
    for (int i = 0; i < 4; ++i)
        #pragma unroll
        for (int j = 0; j < 4; ++j) acc[i][j] = (f32x4){0.f, 0.f, 0.f, 0.f};

    const u16* aP0 = A + (size_t)(m0 + wave * 16 + lr) * C + lg * 8;
    const u16* aP1 = A + (size_t)(m0 + (wave + 4) * 16 + lr) * C + lg * 8;
    const u16* bP0 = Bt + (size_t)bi * S * C + (size_t)(n0 + wave * 16 + lr) * C + lg * 8;
    const u16* bP1 = Bt + (size_t)bi * S * C + (size_t)(n0 + (wave + 4) * 16 + lr) * C + lg * 8;

    for (int k0 = 0; k0 < C; k0 += 32) {
        gload_lds16(aP0 + k0, &As[wave][0]);
        gload_lds16(aP1 + k0, &As[wave + 4][0]);
        gload_lds16(bP0 + k0, &Bs[wave][0]);
        gload_lds16(bP1 + k0, &Bs[wave + 4][0]);
        __syncthreads();
        bf16x8 af[4], bfr[4];
        #pragma unroll
        for (int mf = 0; mf < 4; ++mf) af[mf] = *(bf16x8*)&As[wr * 4 + mf][lane * 8];
        #pragma unroll
        for (int nf = 0; nf < 4; ++nf) bfr[nf] = *(bf16x8*)&Bs[wc * 4 + nf][lane * 8];
        #pragma unroll
        for (int mf = 0; mf < 4; ++mf)
            #pragma unroll
            for (int nf = 0; nf < 4; ++nf)
                acc[mf][nf] = __builtin_amdgcn_mfma_f32_16x16x32_bf16(
                    af[mf], bfr[nf], acc[mf][nf], 0, 0, 0);
        __syncthreads();
    }

    #pragma unroll
    for (int mf = 0; mf < 4; ++mf) {
        const int o3b = m0 + wr * 64 + mf * 16 + 4 * lg;
        float bv[4];
        #pragma unroll
        for (int i = 0; i < 4; ++i) bv[i] = bias[o3b + i];
        #pragma unroll
        for (int nf = 0; nf < 4; ++nf) {
            const int s = n0 + wc * 64 + nf * 16 + lr;
            if (m0 < 512) {          // Q -> Qt[b][h][s][d], scaled by 1/8
                int h = o3b >> 6, d = o3b & 63;
                u16x4 pk;
                #pragma unroll
                for (int i = 0; i < 4; ++i)
                    pk[i] = (u16)f2bf((acc[mf][nf][i] + bv[i]) * 0.125f);
                *(u16x4*)(Qt + (((size_t)bi * 8 + h) * S + s) * 64 + d) = pk;
            } else if (m0 < 1024) {  // K -> Kt[b][h][s][d]
                int ok = o3b - 512;
                int h = ok >> 6, d = ok & 63;
                u16x4 pk;
                #pragma unroll
                for (int i = 0; i < 4; ++i) pk[i] = (u16)f2bf(acc[mf][nf][i] + bv[i]);
                *(u16x4*)(Kt + (((size_t)bi * 8 + h) * S + s) * 64 + d) = pk;
            } else {                 // V -> Vn[b][c][s]
                int ov = o3b - 1024;
                #pragma unroll
                for (int i = 0; i < 4; ++i)
                    Vn[(size_t)(bi * C + ov + i) * S + s] = (u16)f2bf(acc[mf][nf][i] + bv[i]);
            }
        }
    }
}

// Attention. grid (64 bh, 16 qb): bh fast => the 16 qb sharing one (b,h)'s
// K/V map to the same XCD (8 bh per XCD x 256KB = 2MB < 4MB L2).
// K/V double-buffered in LDS via global_load_lds; XOR-swizzled layout
// (pre-swizzled global source, swizzled ds_read) => 2-way max conflicts.
__global__ __launch_bounds__(256) void attn_mfma(
    const u16* __restrict__ Qt, const u16* __restrict__ Kt,
    const u16* __restrict__ Vn, u16* __restrict__ At)
{
    const int bh = blockIdx.x, qb = blockIdx.y;
    const int bi = bh >> 3, h = bh & 7;
    const int tid = threadIdx.x, wave = tid >> 6, lane = tid & 63;
    const int lr = lane & 15, lg = lane >> 4;
    const int q0 = qb * 64 + wave * 16;

    const u16* qt = Qt + ((size_t)bi * 8 + h) * S * 64;
    const u16* kp = Kt + ((size_t)bi * 8 + h) * S * 64;
    const u16* vp = Vn + (size_t)(bi * C + h * 64) * S;

    __shared__ __attribute__((aligned(16))) short Ks[2][4096];  // [64k][64d] swz
    __shared__ __attribute__((aligned(16))) short Vs[2][4096];  // [64d][64k] swz
    __shared__ __attribute__((aligned(16))) short Pf[4][2][64][8];

    bf16x8 aq0 = *(const bf16x8*)(qt + (size_t)(q0 + lr) * 64 + lg * 8);
    bf16x8 aq1 = *(const bf16x8*)(qt + (size_t)(q0 + lr) * 64 + 32 + lg * 8);

    float mrun[4], lrun[4];
    #pragma unroll
    for (int i = 0; i < 4; ++i) { mrun[i] = -1e30f; lrun[i] = 0.f; }
    f32x4 acc[4];
    #pragma unroll
    for (int nf = 0; nf < 4; ++nf) acc[nf] = (f32x4){0.f, 0.f, 0.f, 0.f};

    // stage tile kt0 into buffer buf; LDS slot t=(p*256+tid): row=t/8, col=t&7,
    // source column (col ^ (row&7)) -> linear LDS holds swizzled tile.
    auto STAGE = [&](int buf, int kt0) {
        #pragma unroll
        for (int p = 0; p < 2; ++p) {
            int tp = p * 256 + tid;
            int r = tp >> 3, cs = (tp & 7) ^ (r & 7);
            short* ldsK = &Ks[buf][(p * 256 + (wave << 6)) * 8];
            short* ldsV = &Vs[buf][(p * 256 + (wave << 6)) * 8];
            gload_lds16(kp + (size_t)(kt0 + r) * 64 + cs * 8, ldsK);
            gload_lds16(vp + (size_t)r * S + kt0 + cs * 8, ldsV);
        }
    };

    STAGE(0, 0);
    __syncthreads();

    for (int kt = 0; kt < 16; ++kt) {
        const int cur = kt & 1;
        if (kt < 15) STAGE(cur ^ 1, (kt + 1) * 64);

        // ---- scores: 16q x 64k ----
        f32x4 sc[4];
        #pragma unroll
        for (int kf = 0; kf < 4; ++kf) {
            int rK = kf * 16 + lr;
            bf16x8 b0 = *(bf16x8*)&Ks[cur][rK * 64 + (lg ^ (rK & 7)) * 8];
            bf16x8 b1 = *(bf16x8*)&Ks[cur][rK * 64 + ((lg + 4) ^ (rK & 7)) * 8];
            f32x4 z = (f32x4){0.f, 0.f, 0.f, 0.f};
            z = __builtin_amdgcn_mfma_f32_16x16x32_bf16(aq0, b0, z, 0, 0, 0);
            sc[kf] = __builtin_amdgcn_mfma_f32_16x16x32_bf16(aq1, b1, z, 0, 0, 0);
        }

        // ---- online softmax (row q = 4*lg + i, col k = kf*16 + lr) ----
        float mx[4];
        #pragma unroll
        for (int i = 0; i < 4; ++i)
            mx[i] = fmaxf(fmaxf(sc[0][i], sc[1][i]), fmaxf(sc[2][i], sc[3][i]));
        #pragma unroll
        for (int m = 1; m <= 8; m <<= 1)
            #pragma unroll
            for (int i = 0; i < 4; ++i)
                mx[i] = fmaxf(mx[i], __shfl_xor(mx[i], m));
        float fac[4];
        #pragma unroll
        for (int i = 0; i < 4; ++i) {
            float mnew = fmaxf(mrun[i], mx[i]);
            fac[i] = __expf(mrun[i] - mnew);
            mrun[i] = mnew;
        }
        float sum[4] = {0.f, 0.f, 0.f, 0.f};
        #pragma unroll
        for (int kf = 0; kf < 4; ++kf) {
            #pragma unroll
            for (int i = 0; i < 4; ++i) {
                float pp = __expf(sc[kf][i] - mrun[i]);
                sum[i] += pp;
                float po = __shfl_xor(pp, 1);
                if (!(lr & 1)) {
                    unsigned pk = (unsigned)(u16)f2bf(pp)
                                | ((unsigned)(u16)f2bf(po) << 16);
                    int lanep = (4 * lg + i) + 16 * ((kf & 1) * 2 + (lr >> 3));
                    *(unsigned*)&Pf[wave][kf >> 1][lanep][lr & 7] = pk;
                }
            }
        }
        #pragma unroll
        for (int m = 1; m <= 8; m <<= 1)
            #pragma unroll
            for (int i = 0; i < 4; ++i)
                sum[i] += __shfl_xor(sum[i], m);
        f32x4 ffac;
        #pragma unroll
        for (int i = 0; i < 4; ++i) {
            lrun[i] = lrun[i] * fac[i] + sum[i];
            ffac[i] = fac[i];
        }
        #pragma unroll
        for (int nf = 0; nf < 4; ++nf) acc[nf] *= ffac;

        // ---- PV ----
        bf16x8 pa0 = *(bf16x8*)&Pf[wave][0][lane][0];
        bf16x8 pa1 = *(bf16x8*)&Pf[wave][1][lane][0];
        #pragma unroll
        for (int nf = 0; nf < 4; ++nf) {
            int rV = nf * 16 + lr;
            bf16x8 v0 = *(bf16x8*)&Vs[cur][rV * 64 + (lg ^ (rV & 7)) * 8];
            bf16x8 v1 = *(bf16x8*)&Vs[cur][rV * 64 + ((lg + 4) ^ (rV & 7)) * 8];
            acc[nf] = __builtin_amdgcn_mfma_f32_16x16x32_bf16(pa0, v0, acc[nf], 0, 0, 0);
            acc[nf] = __builtin_amdgcn_mfma_f32_16x16x32_bf16(pa1, v1, acc[nf], 0, 0, 0);
        }
        __syncthreads();   // drains next-tile stage loads + LDS ops
    }

    float linv[4];
    #pragma unroll
    for (int i = 0; i < 4; ++i) linv[i] = 1.f / lrun[i];
    #pragma unroll
    for (int nf = 0; nf < 4; ++nf)
        #pragma unroll
        for (int i = 0; i < 4; ++i)
            At[((size_t)bi * S + q0 + 4 * lg + i) * C + h * 64 + nf * 16 + lr] =
                (u16)f2bf(acc[nf][i] * linv[i]);
}

// proj: A=Wp[512][512] x Bt=attn_t[s][c] + bias + residual -> fp32 out
__global__ __launch_bounds__(256) void proj_mfma(
    const u16* __restrict__ A, const u16* __restrict__ Bt,
    const float* __restrict__ bias, const float* __restrict__ Xres,
    float* __restrict__ out)
{
    const int n0 = blockIdx.x * 128, m0 = blockIdx.y * 128;
    const int bi = blockIdx.z;
    const int tid = threadIdx.x, wave = tid >> 6, lane = tid & 63;
    const int lr = lane & 15, lg = lane >> 4;
    const int wr = wave >> 1, wc = wave & 1;

    __shared__ __attribute__((aligned(16))) short As[8][512];
    __shared__ __attribute__((aligned(16))) short Bs[8][512];

    f32x4 acc[4][4];
    #pragma unroll
    for (int i = 0; i < 4; ++i)
        #pragma unroll
        for (int j = 0; j < 4; ++j) acc[i][j] = (f32x4){0.f, 0.f, 0.f, 0.f};

    const u16* aP0 = A + (size_t)(m0 + wave * 16 + lr) * C + lg * 8;
    const u16* aP1 = A + (size_t)(m0 + (wave + 4) * 16 + lr) * C + lg * 8;
    const u16* bP0 = Bt + (size_t)bi * S * C + (size_t)(n0 + wave * 16 + lr) * C + lg * 8;
    const u16* bP1 = Bt + (size_t)bi * S * C + (size_t)(n0 + (wave + 4) * 16 + lr) * C + lg * 8;

    for (int k0 = 0; k0 < C; k0 += 32) {
        gload_lds16(aP0 + k0, &As[wave][0]);
        gload_lds16(aP1 + k0, &As[wave + 4][0]);
        gload_lds16(bP0 + k0, &Bs[wave][0]);
        gload_lds16(bP1 + k0, &Bs[wave + 4][0]);
        __syncthreads();
        bf16x8 af[4], bfr[4];
        #pragma unroll
        for (int mf = 0; mf < 4; ++mf) af[mf] = *(bf16x8*)&As[wr * 4 + mf][lane * 8];
        #pragma unroll
        for (int nf = 0; nf < 4; ++nf) bfr[nf] = *(bf16x8*)&Bs[wc * 4 + nf][lane * 8];
        #pragma unroll
        for (int mf = 0; mf < 4; ++mf)
            #pragma unroll
            for (int nf = 0; nf < 4; ++nf)
                acc[mf][nf] = __builtin_amdgcn_mfma_f32_16x16x32_bf16(
                    af[mf], bfr[nf], acc[mf][nf], 0, 0, 0);
        __syncthreads();
    }

    #pragma unroll
    for (int mf = 0; mf < 4; ++mf) {
        const int ob = m0 + wr * 64 + mf * 16 + 4 * lg;
        float bv[4];
        #pragma unroll
        for (int i = 0; i < 4; ++i) bv[i] = bias[ob + i];
        #pragma unroll
        for (int nf = 0; nf < 4; ++nf) {
            const int s = n0 + wc * 64 + nf * 16 + lr;
            #pragma unroll
            for (int i = 0; i < 4; ++i) {
                size_t oi = ((size_t)bi * C + ob + i) * S + s;
                out[oi] = acc[mf][nf][i] + bv[i] + Xres[oi];
            }
        }
    }
}

extern "C" void kernel_launch(void* const* d_in, const int* in_sizes, int n_in,
                              void* d_out, int out_size, void* d_ws, size_t ws_size,
                              hipStream_t stream) {
    const float* X      = (const float*)d_in[0];
    const float* norm_w = (const float*)d_in[1];
    const float* norm_b = (const float*)d_in[2];
    const float* qkv_w  = (const float*)d_in[3];
    const float* qkv_b  = (const float*)d_in[4];
    const float* proj_w = (const float*)d_in[5];
    const float* proj_b = (const float*)d_in[6];
    float* out = (float*)d_out;

    float* scaleA = (float*)d_ws;              // 4096 f
    float* shiftB = scaleA + 4096;             // 4096 f
    u16* Wq_bf = (u16*)(shiftB + 4096);        // 1536*512
    u16* Wp_bf = Wq_bf + 786432;               // 512*512
    u16* Xn_t  = Wp_bf + 262144;               // 8*1024*512
    u16* Qt    = Xn_t + 4194304;               // 8*8*1024*64
    u16* Kt    = Qt + 4194304;
    u16* Vn    = Kt + 4194304;                 // 8*512*1024
    u16* At    = Vn + 4194304;                 // 8*1024*512

    gn_stats<<<dim3(BATCH * 32), 256, 0, stream>>>(X, norm_w, norm_b, scaleA, shiftB);
    wconv<<<dim3(384), 256, 0, stream>>>(qkv_w, Wq_bf, 98304);
    wconv<<<dim3(128), 256, 0, stream>>>(proj_w, Wp_bf, 32768);
    xnt_kernel<<<dim3(S / 64, C / 64, BATCH), 256, 0, stream>>>(X, scaleA, shiftB, Xn_t);
    qkv_mfma<<<dim3(S / 128, OC3 / 128, BATCH), 256, 0, stream>>>(
        Wq_bf, Xn_t, qkv_b, Qt, Kt, Vn);
    attn_mfma<<<dim3(64, S / 64), 256, 0, stream>>>(Qt, Kt, Vn, At);
    proj_mfma<<<dim3(S / 128, C / 128, BATCH), 256, 0, stream>>>(
        Wp_bf, At, proj_b, X, out);
}

// Round 5
// 126.581 us; speedup vs baseline: 8.0488x; 1.2505x over previous
//
#include <hip/hip_runtime.h>
#include <hip/hip_bf16.h>

// AttentionBlock  B=8, C=512, H=W=32 (S=1024), heads=8, hd=64, groups=32
// Round 5: swapped-operand attention (q lane-local softmax, T12), P via
// cvt_pk + swizzled ds_write_b64; 2-phase double-buffered GEMMs.

#define BATCH 8
#define C 512
#define S 1024
#define HEADS 8
#define OC3 1536

typedef short bf16x8 __attribute__((ext_vector_type(8)));
typedef float f32x4 __attribute__((ext_vector_type(4)));
typedef unsigned u32x2 __attribute__((ext_vector_type(2)));
typedef unsigned short u16;
typedef unsigned short u16x4 __attribute__((ext_vector_type(4)));

__device__ inline short f2bf(float x) {
    union { float f; unsigned u; } v; v.f = x;
    unsigned r = v.u + 0x7fffu + ((v.u >> 16) & 1u);   // RNE
    return (short)(r >> 16);
}

__device__ inline unsigned cvt_pk_bf16(float lo, float hi) {
    unsigned r;
    asm("v_cvt_pk_bf16_f32 %0, %1, %2" : "=v"(r) : "v"(lo), "v"(hi));
    return r;
}

__device__ inline void gload_lds16(const u16* g, short* l) {
    __builtin_amdgcn_global_load_lds(
        (const __attribute__((address_space(1))) unsigned int*)g,
        (__attribute__((address_space(3))) unsigned int*)l, 16, 0, 0);
}

__global__ __launch_bounds__(256) void gn_stats(
    const float* __restrict__ X, const float* __restrict__ nw,
    const float* __restrict__ nb, float* __restrict__ scaleA,
    float* __restrict__ shiftB)
{
    const int blk = blockIdx.x;
    const int bi = blk >> 5, g = blk & 31;
    const int tid = threadIdx.x;
    const size_t base = ((size_t)bi * C + g * 16) * S;
    float s = 0.f, ss = 0.f;
    for (int i = tid; i < 16 * S; i += 256) {
        float v = X[base + i];
        s += v; ss += v * v;
    }
    __shared__ float rs[256], rss[256];
    rs[tid] = s; rss[tid] = ss;
    __syncthreads();
    for (int off = 128; off > 0; off >>= 1) {
        if (tid < off) { rs[tid] += rs[tid + off]; rss[tid] += rss[tid + off]; }
        __syncthreads();
    }
    __shared__ float sh_mean, sh_rstd;
    if (tid == 0) {
        float mean = rs[0] * (1.f / (16 * S));
        float var = rss[0] * (1.f / (16 * S)) - mean * mean;
        sh_mean = mean;
        sh_rstd = rsqrtf(var + 1e-5f);
    }
    __syncthreads();
    if (tid < 16) {
        int c = g * 16 + tid;
        float rw = sh_rstd * nw[c];
        scaleA[bi * C + c] = rw;
        shiftB[bi * C + c] = nb[c] - sh_mean * rw;
    }
}

__global__ __launch_bounds__(256) void wconv(
    const float* __restrict__ w, u16* __restrict__ o, int n8)
{
    int i = blockIdx.x * 256 + threadIdx.x;
    if (i < n8) {
        f32x4 a = *(const f32x4*)(w + (size_t)i * 8);
        f32x4 b = *(const f32x4*)(w + (size_t)i * 8 + 4);
        bf16x8 r;
        #pragma unroll
        for (int j = 0; j < 4; ++j) { r[j] = f2bf(a[j]); r[4 + j] = f2bf(b[j]); }
        *(bf16x8*)(o + (size_t)i * 8) = r;
    }
}

// Xn_t[b][s][c] = bf16(X[b][c][s]*scaleA + shiftB). Tile 64c x 64s.
__global__ __launch_bounds__(256) void xnt_kernel(
    const float* __restrict__ X, const float* __restrict__ scaleA,
    const float* __restrict__ shiftB, u16* __restrict__ Xn_t)
{
    const int s0 = blockIdx.x * 64, c0 = blockIdx.y * 64, bi = blockIdx.z;
    const int tid = threadIdx.x;
    __shared__ float T[64][65];
    #pragma unroll
    for (int p = 0; p < 4; ++p) {
        int c = p * 16 + (tid >> 4);
        int sl = (tid & 15) * 4;
        float sa = scaleA[bi * C + c0 + c];
        float sb = shiftB[bi * C + c0 + c];
        f32x4 v = *(const f32x4*)(X + ((size_t)bi * C + c0 + c) * S + s0 + sl);
        #pragma unroll
        for (int j = 0; j < 4; ++j) T[c][sl + j] = v[j] * sa + sb;
    }
    __syncthreads();
    #pragma unroll
    for (int p = 0; p < 2; ++p) {
        int s = p * 32 + (tid >> 3);
        int cc = tid & 7;
        bf16x8 o;
        #pragma unroll
        for (int j = 0; j < 8; ++j) o[j] = f2bf(T[cc * 8 + j][s]);
        *(bf16x8*)(Xn_t + (size_t)bi * S * C + (size_t)(s0 + s) * C + c0 + cc * 8) = o;
    }
}

// GEMM: A[M][K] bf16 x Bt[N][K] bf16. 128x128 tile, BK=32, 4 waves,
// double-buffered LDS, STAGE(next) before compute, 1 barrier/iter.
// Q region epilogue folds the 1/8 attention scale.
__global__ __launch_bounds__(256) void qkv_mfma(
    const u16* __restrict__ A, const u16* __restrict__ Bt,
    const float* __restrict__ bias,
    u16* __restrict__ Qt, u16* __restrict__ Kt, u16* __restrict__ Vn)
{
    const int n0 = blockIdx.x * 128, m0 = blockIdx.y * 128;
    const int bi = blockIdx.z;
    const int tid = threadIdx.x, wave = tid >> 6, lane = tid & 63;
    const int lr = lane & 15, lg = lane >> 4;
    const int wr = wave >> 1, wc = wave & 1;

    __shared__ __attribute__((aligned(16))) short As[2][8][512];
    __shared__ __attribute__((aligned(16))) short Bs[2][8][512];

    f32x4 acc[4][4];
    #pragma unroll
    for (int i = 0; i < 4; ++i)
        #pragma unroll
        for (int j = 0; j < 4; ++j) acc[i][j] = (f32x4){0.f, 0.f, 0.f, 0.f};

    const u16* aP0 = A + (size_t)(m0 + wave * 16 + lr) * C + lg * 8;
    const u16* aP1 = A + (size_t)(m0 + (wave + 4) * 16 + lr) * C + lg * 8;
    const u16* bP0 = Bt + (size_t)bi * S * C + (size_t)(n0 + wave * 16 + lr) * C + lg * 8;
    const u16* bP1 = Bt + (size_t)bi * S * C + (size_t)(n0 + (wave + 4) * 16 + lr) * C + lg * 8;

    auto STAGE = [&](int buf, int k0) {
        gload_lds16(aP0 + k0, &As[buf][wave][0]);
        gload_lds16(aP1 + k0, &As[buf][wave + 4][0]);
        gload_lds16(bP0 + k0, &Bs[buf][wave][0]);
        gload_lds16(bP1 + k0, &Bs[buf][wave + 4][0]);
    };

    STAGE(0, 0);
    __syncthreads();

    for (int kt = 0; kt < 16; ++kt) {
        const int cur = kt & 1;
        if (kt < 15) STAGE(cur ^ 1, (kt + 1) * 32);
        bf16x8 af[4], bfr[4];
        #pragma unroll
        for (int mf = 0; mf < 4; ++mf) af[mf] = *(bf16x8*)&As[cur][wr * 4 + mf][lane * 8];
        #pragma unroll
        for (int nf = 0; nf < 4; ++nf) bfr[nf] = *(bf16x8*)&Bs[cur][wc * 4 + nf][lane * 8];
        #pragma unroll
        for (int mf = 0; mf < 4; ++mf)
            #pragma unroll
            for (int nf = 0; nf < 4; ++nf)
                acc[mf][nf] = __builtin_amdgcn_mfma_f32_16x16x32_bf16(
                    af[mf], bfr[nf], acc[mf][nf], 0, 0, 0);
        __syncthreads();
    }

    #pragma unroll
    for (int mf = 0; mf < 4; ++mf) {
        const int o3b = m0 + wr * 64 + mf * 16 + 4 * lg;
        float bv[4];
        #pragma unroll
        for (int i = 0; i < 4; ++i) bv[i] = bias[o3b + i];
        #pragma unroll
        for (int nf = 0; nf < 4; ++nf) {
            const int s = n0 + wc * 64 + nf * 16 + lr;
            if (m0 < 512) {          // Q -> Qt[b][h][s][d], scaled by 1/8
                int h = o3b >> 6, d = o3b & 63;
                u16x4 pk;
                #pragma unroll
                for (int i = 0; i < 4; ++i)
                    pk[i] = (u16)f2bf((acc[mf][nf][i] + bv[i]) * 0.125f);
                *(u16x4*)(Qt + (((size_t)bi * 8 + h) * S + s) * 64 + d) = pk;
            } else if (m0 < 1024) {  // K -> Kt[b][h][s][d]
                int ok = o3b - 512;
                int h = ok >> 6, d = ok & 63;
                u16x4 pk;
                #pragma unroll
                for (int i = 0; i < 4; ++i) pk[i] = (u16)f2bf(acc[mf][nf][i] + bv[i]);
                *(u16x4*)(Kt + (((size_t)bi * 8 + h) * S + s) * 64 + d) = pk;
            } else {                 // V -> Vn[b][c][s]
                int ov = o3b - 1024;
                #pragma unroll
                for (int i = 0; i < 4; ++i)
                    Vn[(size_t)(bi * C + ov + i) * S + s] = (u16)f2bf(acc[mf][nf][i] + bv[i]);
            }
        }
    }
}

// Attention, swapped operands. grid (64 bh, 16 qb), bh fast (XCD-local K/V).
// QK^T: sc = mfma(K, Q) -> q = lane&15 (lane-local row), k = 4*lg + i + 16*kf.
// Softmax: in-register + 2 shuffles; mrun/lrun/fac scalar per lane.
// P: cvt_pk pairs -> 4x ds_write_b64 into chunk-swizzled per-wave buffer;
// PV: acc = mfma(V, P) -> O^T fragment (q = lane&15, d = rows).
__global__ __launch_bounds__(256) void attn_mfma(
    const u16* __restrict__ Qt, const u16* __restrict__ Kt,
    const u16* __restrict__ Vn, u16* __restrict__ At)
{
    const int bh = blockIdx.x, qb = blockIdx.y;
    const int bi = bh >> 3, h = bh & 7;
    const int tid = threadIdx.x, wave = tid >> 6, lane = tid & 63;
    const int lr = lane & 15, lg = lane >> 4;
    const int q0 = qb * 64 + wave * 16;

    const u16* qt = Qt + ((size_t)bi * 8 + h) * S * 64;
    const u16* kp = Kt + ((size_t)bi * 8 + h) * S * 64;
    const u16* vp = Vn + (size_t)(bi * C + h * 64) * S;

    __shared__ __attribute__((aligned(16))) short Ks[2][4096];  // [64k][64d] swz
    __shared__ __attribute__((aligned(16))) short Vs[2][4096];  // [64d][64k] swz
    __shared__ __attribute__((aligned(16))) short Pw[4][16][64]; // per-wave P, swz

    bf16x8 aq0 = *(const bf16x8*)(qt + (size_t)(q0 + lr) * 64 + lg * 8);
    bf16x8 aq1 = *(const bf16x8*)(qt + (size_t)(q0 + lr) * 64 + 32 + lg * 8);

    float mrun = -1e30f, lrun = 0.f;
    f32x4 acc[4];
    #pragma unroll
    for (int df = 0; df < 4; ++df) acc[df] = (f32x4){0.f, 0.f, 0.f, 0.f};

    auto STAGE = [&](int buf, int kt0) {
        #pragma unroll
        for (int p = 0; p < 2; ++p) {
            int tp = p * 256 + tid;
            int r = tp >> 3, cs = (tp & 7) ^ (r & 7);
            short* ldsK = &Ks[buf][(p * 256 + (wave << 6)) * 8];
            short* ldsV = &Vs[buf][(p * 256 + (wave << 6)) * 8];
            gload_lds16(kp + (size_t)(kt0 + r) * 64 + cs * 8, ldsK);
            gload_lds16(vp + (size_t)r * S + kt0 + cs * 8, ldsV);
        }
    };

    unsigned* pwb = (unsigned*)&Pw[wave][0][0];
    const int rsw = lr & 7;

    STAGE(0, 0);
    __syncthreads();

    for (int kt = 0; kt < 16; ++kt) {
        const int cur = kt & 1;
        if (kt < 15) STAGE(cur ^ 1, (kt + 1) * 64);

        // ---- scores (swapped): sc[kf][i] = S^T[k=kf*16+4lg+i][q=lr] ----
        f32x4 sc[4];
        #pragma unroll
        for (int kf = 0; kf < 4; ++kf) {
            int rK = kf * 16 + lr;
            bf16x8 b0 = *(bf16x8*)&Ks[cur][rK * 64 + (lg ^ (rK & 7)) * 8];
            bf16x8 b1 = *(bf16x8*)&Ks[cur][rK * 64 + ((lg + 4) ^ (rK & 7)) * 8];
            f32x4 z = (f32x4){0.f, 0.f, 0.f, 0.f};
            z = __builtin_amdgcn_mfma_f32_16x16x32_bf16(b0, aq0, z, 0, 0, 0);
            sc[kf] = __builtin_amdgcn_mfma_f32_16x16x32_bf16(b1, aq1, z, 0, 0, 0);
        }

        // ---- softmax: row q = lr is lane-local ----
        float tmax = sc[0][0];
        #pragma unroll
        for (int kf = 0; kf < 4; ++kf)
            #pragma unroll
            for (int i = 0; i < 4; ++i) tmax = fmaxf(tmax, sc[kf][i]);
        tmax = fmaxf(tmax, __shfl_xor(tmax, 16));
        tmax = fmaxf(tmax, __shfl_xor(tmax, 32));
        float mnew = fmaxf(mrun, tmax);
        float fac = __expf(mrun - mnew);
        mrun = mnew;

        float sum = 0.f;
        #pragma unroll
        for (int kf = 0; kf < 4; ++kf)
            #pragma unroll
            for (int i = 0; i < 4; ++i) {
                sc[kf][i] = __expf(sc[kf][i] - mrun);
                sum += sc[kf][i];
            }

        // ---- P pack + swizzled write (4x ds_write_b64) ----
        #pragma unroll
        for (int kf = 0; kf < 4; ++kf) {
            unsigned p0 = cvt_pk_bf16(sc[kf][0], sc[kf][1]);
            unsigned p1 = cvt_pk_bf16(sc[kf][2], sc[kf][3]);
            int c0 = kf * 8 + 2 * lg;                    // u32 col, even
            int idx = lr * 32 + ((c0 >> 2) ^ rsw) * 4 + (c0 & 3);
            *(u32x2*)&pwb[idx] = (u32x2){p0, p1};
        }

        sum += __shfl_xor(sum, 16);
        sum += __shfl_xor(sum, 32);
        lrun = lrun * fac + sum;
        #pragma unroll
        for (int df = 0; df < 4; ++df) acc[df] *= fac;

        // ---- PV (swapped): B = P[q=lr][k chunk], A = V[d][k chunk] ----
        bf16x8 pb0 = *(bf16x8*)&Pw[wave][lr][(lg ^ rsw) * 8];
        bf16x8 pb1 = *(bf16x8*)&Pw[wave][lr][((4 + lg) ^ rsw) * 8];
        #pragma unroll
        for (int df = 0; df < 4; ++df) {
            int rV = df * 16 + lr;
            bf16x8 v0 = *(bf16x8*)&Vs[cur][rV * 64 + (lg ^ (rV & 7)) * 8];
            bf16x8 v1 = *(bf16x8*)&Vs[cur][rV * 64 + ((lg + 4) ^ (rV & 7)) * 8];
            acc[df] = __builtin_amdgcn_mfma_f32_16x16x32_bf16(v0, pb0, acc[df], 0, 0, 0);
            acc[df] = __builtin_amdgcn_mfma_f32_16x16x32_bf16(v1, pb1, acc[df], 0, 0, 0);
        }
        __syncthreads();   // drains next-tile stage loads; guards buffer reuse
    }

    // ---- epilogue: lane q = q0+lr, d = df*16 + 4*lg + i (4 consecutive) ----
    float linv = 1.f / lrun;
    #pragma unroll
    for (int df = 0; df < 4; ++df) {
        u16x4 pk;
        #pragma unroll
        for (int i = 0; i < 4; ++i) pk[i] = (u16)f2bf(acc[df][i] * linv);
        *(u16x4*)(At + ((size_t)bi * S + q0 + lr) * C + h * 64 + df * 16 + 4 * lg) = pk;
    }
}

// proj: A=Wp[512][512] x Bt=attn_t[s][c] + bias + residual -> fp32 out
__global__ __launch_bounds__(256) void proj_mfma(
    const u16* __restrict__ A, const u16* __restrict__ Bt,
    const float* __restrict__ bias, const float* __restrict__ Xres,
    float* __restrict__ out)
{
    const int n0 = blockIdx.x * 128, m0 = blockIdx.y * 128;
    const int bi = blockIdx.z;
    const int tid = threadIdx.x, wave = tid >> 6, lane = tid & 63;
    const int lr = lane & 15, lg = lane >> 4;
    const int wr = wave >> 1, wc = wave & 1;

    __shared__ __attribute__((aligned(16))) short As[2][8][512];
    __shared__ __attribute__((aligned(16))) short Bs[2][8][512];

    f32x4 acc[4][4];
    #pragma unroll
    for (int i = 0; i < 4; ++i)
        #pragma unroll
        for (int j = 0; j < 4; ++j) acc[i][j] = (f32x4){0.f, 0.f, 0.f, 0.f};

    const u16* aP0 = A + (size_t)(m0 + wave * 16 + lr) * C + lg * 8;
    const u16* aP1 = A + (size_t)(m0 + (wave + 4) * 16 + lr) * C + lg * 8;
    const u16* bP0 = Bt + (size_t)bi * S * C + (size_t)(n0 + wave * 16 + lr) * C + lg * 8;
    const u16* bP1 = Bt + (size_t)bi * S * C + (size_t)(n0 + (wave + 4) * 16 + lr) * C + lg * 8;

    auto STAGE = [&](int buf, int k0) {
        gload_lds16(aP0 + k0, &As[buf][wave][0]);
        gload_lds16(aP1 + k0, &As[buf][wave + 4][0]);
        gload_lds16(bP0 + k0, &Bs[buf][wave][0]);
        gload_lds16(bP1 + k0, &Bs[buf][wave + 4][0]);
    };

    STAGE(0, 0);
    __syncthreads();

    for (int kt = 0; kt < 16; ++kt) {
        const int cur = kt & 1;
        if (kt < 15) STAGE(cur ^ 1, (kt + 1) * 32);
        bf16x8 af[4], bfr[4];
        #pragma unroll
        for (int mf = 0; mf < 4; ++mf) af[mf] = *(bf16x8*)&As[cur][wr * 4 + mf][lane * 8];
        #pragma unroll
        for (int nf = 0; nf < 4; ++nf) bfr[nf] = *(bf16x8*)&Bs[cur][wc * 4 + nf][lane * 8];
        #pragma unroll
        for (int mf = 0; mf < 4; ++mf)
            #pragma unroll
            for (int nf = 0; nf < 4; ++nf)
                acc[mf][nf] = __builtin_amdgcn_mfma_f32_16x16x32_bf16(
                    af[mf], bfr[nf], acc[mf][nf], 0, 0, 0);
        __syncthreads();
    }

    #pragma unroll
    for (int mf = 0; mf < 4; ++mf) {
        const int ob = m0 + wr * 64 + mf * 16 + 4 * lg;
        float bv[4];
        #pragma unroll
        for (int i = 0; i < 4; ++i) bv[i] = bias[ob + i];
        #pragma unroll
        for (int nf = 0; nf < 4; ++nf) {
            const int s = n0 + wc * 64 + nf * 16 + lr;
            #pragma unroll
            for (int i = 0; i < 4; ++i) {
                size_t oi = ((size_t)bi * C + ob + i) * S + s;
                out[oi] = acc[mf][nf][i] + bv[i] + Xres[oi];
            }
        }
    }
}

extern "C" void kernel_launch(void* const* d_in, const int* in_sizes, int n_in,
                              void* d_out, int out_size, void* d_ws, size_t ws_size,
                              hipStream_t stream) {
    const float* X      = (const float*)d_in[0];
    const float* norm_w = (const float*)d_in[1];
    const float* norm_b = (const float*)d_in[2];
    const float* qkv_w  = (const float*)d_in[3];
    const float* qkv_b  = (const float*)d_in[4];
    const float* proj_w = (const float*)d_in[5];
    const float* proj_b = (const float*)d_in[6];
    float* out = (float*)d_out;

    float* scaleA = (float*)d_ws;              // 4096 f
    float* shiftB = scaleA + 4096;             // 4096 f
    u16* Wq_bf = (u16*)(shiftB + 4096);        // 1536*512
    u16* Wp_bf = Wq_bf + 786432;               // 512*512
    u16* Xn_t  = Wp_bf + 262144;               // 8*1024*512
    u16* Qt    = Xn_t + 4194304;               // 8*8*1024*64
    u16* Kt    = Qt + 4194304;
    u16* Vn    = Kt + 4194304;                 // 8*512*1024
    u16* At    = Vn + 4194304;                 // 8*1024*512

    gn_stats<<<dim3(BATCH * 32), 256, 0, stream>>>(X, norm_w, norm_b, scaleA, shiftB);
    wconv<<<dim3(384), 256, 0, stream>>>(qkv_w, Wq_bf, 98304);
    wconv<<<dim3(128), 256, 0, stream>>>(proj_w, Wp_bf, 32768);
    xnt_kernel<<<dim3(S / 64, C / 64, BATCH), 256, 0, stream>>>(X, scaleA, shiftB, Xn_t);
    qkv_mfma<<<dim3(S / 128, OC3 / 128, BATCH), 256, 0, stream>>>(
        Wq_bf, Xn_t, qkv_b, Qt, Kt, Vn);
    attn_mfma<<<dim3(64, S / 64), 256, 0, stream>>>(Qt, Kt, Vn, At);
    proj_mfma<<<dim3(S / 128, C / 128, BATCH), 256, 0, stream>>>(
        Wp_bf, At, proj_b, X, out);
}

// Round 6
// 105.956 us; speedup vs baseline: 9.6156x; 1.1947x over previous
//
#include <hip/hip_runtime.h>
#include <hip/hip_bf16.h>

// AttentionBlock  B=8, C=512, H=W=32 (S=1024), heads=8, hd=64, groups=32
// Round 6: attn -> 8-wave blocks (128 q/block, 75% occ), exp2-domain softmax
// (log2e folded into Q), defer-max (THR=8), setprio around MFMA clusters.
// gn_stats vectorized. GEMMs unchanged from round 5.

#define BATCH 8
#define C 512
#define S 1024
#define HEADS 8
#define OC3 1536

typedef short bf16x8 __attribute__((ext_vector_type(8)));
typedef float f32x4 __attribute__((ext_vector_type(4)));
typedef unsigned u32x2 __attribute__((ext_vector_type(2)));
typedef unsigned short u16;
typedef unsigned short u16x4 __attribute__((ext_vector_type(4)));

__device__ inline short f2bf(float x) {
    union { float f; unsigned u; } v; v.f = x;
    unsigned r = v.u + 0x7fffu + ((v.u >> 16) & 1u);   // RNE
    return (short)(r >> 16);
}

__device__ inline unsigned cvt_pk_bf16(float lo, float hi) {
    unsigned r;
    asm("v_cvt_pk_bf16_f32 %0, %1, %2" : "=v"(r) : "v"(lo), "v"(hi));
    return r;
}

__device__ inline void gload_lds16(const u16* g, short* l) {
    __builtin_amdgcn_global_load_lds(
        (const __attribute__((address_space(1))) unsigned int*)g,
        (__attribute__((address_space(3))) unsigned int*)l, 16, 0, 0);
}

__global__ __launch_bounds__(256) void gn_stats(
    const float* __restrict__ X, const float* __restrict__ nw,
    const float* __restrict__ nb, float* __restrict__ scaleA,
    float* __restrict__ shiftB)
{
    const int blk = blockIdx.x;
    const int bi = blk >> 5, g = blk & 31;
    const int tid = threadIdx.x;
    const size_t base = ((size_t)bi * C + g * 16) * S;
    const f32x4* Xv = (const f32x4*)(X + base);     // 4096 float4 per group
    float s = 0.f, ss = 0.f;
    #pragma unroll 4
    for (int i = tid; i < 4096; i += 256) {
        f32x4 v = Xv[i];
        s  += v[0] + v[1] + v[2] + v[3];
        ss += v[0]*v[0] + v[1]*v[1] + v[2]*v[2] + v[3]*v[3];
    }
    __shared__ float rs[256], rss[256];
    rs[tid] = s; rss[tid] = ss;
    __syncthreads();
    for (int off = 128; off > 0; off >>= 1) {
        if (tid < off) { rs[tid] += rs[tid + off]; rss[tid] += rss[tid + off]; }
        __syncthreads();
    }
    __shared__ float sh_mean, sh_rstd;
    if (tid == 0) {
        float mean = rs[0] * (1.f / (16 * S));
        float var = rss[0] * (1.f / (16 * S)) - mean * mean;
        sh_mean = mean;
        sh_rstd = rsqrtf(var + 1e-5f);
    }
    __syncthreads();
    if (tid < 16) {
        int c = g * 16 + tid;
        float rw = sh_rstd * nw[c];
        scaleA[bi * C + c] = rw;
        shiftB[bi * C + c] = nb[c] - sh_mean * rw;
    }
}

__global__ __launch_bounds__(256) void wconv(
    const float* __restrict__ w, u16* __restrict__ o, int n8)
{
    int i = blockIdx.x * 256 + threadIdx.x;
    if (i < n8) {
        f32x4 a = *(const f32x4*)(w + (size_t)i * 8);
        f32x4 b = *(const f32x4*)(w + (size_t)i * 8 + 4);
        bf16x8 r;
        #pragma unroll
        for (int j = 0; j < 4; ++j) { r[j] = f2bf(a[j]); r[4 + j] = f2bf(b[j]); }
        *(bf16x8*)(o + (size_t)i * 8) = r;
    }
}

// Xn_t[b][s][c] = bf16(X[b][c][s]*scaleA + shiftB). Tile 64c x 64s.
__global__ __launch_bounds__(256) void xnt_kernel(
    const float* __restrict__ X, const float* __restrict__ scaleA,
    const float* __restrict__ shiftB, u16* __restrict__ Xn_t)
{
    const int s0 = blockIdx.x * 64, c0 = blockIdx.y * 64, bi = blockIdx.z;
    const int tid = threadIdx.x;
    __shared__ float T[64][65];
    #pragma unroll
    for (int p = 0; p < 4; ++p) {
        int c = p * 16 + (tid >> 4);
        int sl = (tid & 15) * 4;
        float sa = scaleA[bi * C + c0 + c];
        float sb = shiftB[bi * C + c0 + c];
        f32x4 v = *(const f32x4*)(X + ((size_t)bi * C + c0 + c) * S + s0 + sl);
        #pragma unroll
        for (int j = 0; j < 4; ++j) T[c][sl + j] = v[j] * sa + sb;
    }
    __syncthreads();
    #pragma unroll
    for (int p = 0; p < 2; ++p) {
        int s = p * 32 + (tid >> 3);
        int cc = tid & 7;
        bf16x8 o;
        #pragma unroll
        for (int j = 0; j < 8; ++j) o[j] = f2bf(T[cc * 8 + j][s]);
        *(bf16x8*)(Xn_t + (size_t)bi * S * C + (size_t)(s0 + s) * C + c0 + cc * 8) = o;
    }
}

// GEMM: A[M][K] bf16 x Bt[N][K] bf16. 128x128 tile, BK=32, 4 waves,
// double-buffered LDS, STAGE(next) before compute, 1 barrier/iter.
// Q epilogue folds 0.125*log2(e): attention runs in exp2 domain.
__global__ __launch_bounds__(256) void qkv_mfma(
    const u16* __restrict__ A, const u16* __restrict__ Bt,
    const float* __restrict__ bias,
    u16* __restrict__ Qt, u16* __restrict__ Kt, u16* __restrict__ Vn)
{
    const int n0 = blockIdx.x * 128, m0 = blockIdx.y * 128;
    const int bi = blockIdx.z;
    const int tid = threadIdx.x, wave = tid >> 6, lane = tid & 63;
    const int lr = lane & 15, lg = lane >> 4;
    const int wr = wave >> 1, wc = wave & 1;

    __shared__ __attribute__((aligned(16))) short As[2][8][512];
    __shared__ __attribute__((aligned(16))) short Bs[2][8][512];

    f32x4 acc[4][4];
    #pragma unroll
    for (int i = 0; i < 4; ++i)
        #pragma unroll
        for (int j = 0; j < 4; ++j) acc[i][j] = (f32x4){0.f, 0.f, 0.f, 0.f};

    const u16* aP0 = A + (size_t)(m0 + wave * 16 + lr) * C + lg * 8;
    const u16* aP1 = A + (size_t)(m0 + (wave + 4) * 16 + lr) * C + lg * 8;
    const u16* bP0 = Bt + (size_t)bi * S * C + (size_t)(n0 + wave * 16 + lr) * C + lg * 8;
    const u16* bP1 = Bt + (size_t)bi * S * C + (size_t)(n0 + (wave + 4) * 16 + lr) * C + lg * 8;

    auto STAGE = [&](int buf, int k0) {
        gload_lds16(aP0 + k0, &As[buf][wave][0]);
        gload_lds16(aP1 + k0, &As[buf][wave + 4][0]);
        gload_lds16(bP0 + k0, &Bs[buf][wave][0]);
        gload_lds16(bP1 + k0, &Bs[buf][wave + 4][0]);
    };

    STAGE(0, 0);
    __syncthreads();

    for (int kt = 0; kt < 16; ++kt) {
        const int cur = kt & 1;
        if (kt < 15) STAGE(cur ^ 1, (kt + 1) * 32);
        bf16x8 af[4], bfr[4];
        #pragma unroll
        for (int mf = 0; mf < 4; ++mf) af[mf] = *(bf16x8*)&As[cur][wr * 4 + mf][lane * 8];
        #pragma unroll
        for (int nf = 0; nf < 4; ++nf) bfr[nf] = *(bf16x8*)&Bs[cur][wc * 4 + nf][lane * 8];
        __builtin_amdgcn_s_setprio(1);
        #pragma unroll
        for (int mf = 0; mf < 4; ++mf)
            #pragma unroll
            for (int nf = 0; nf < 4; ++nf)
                acc[mf][nf] = __builtin_amdgcn_mfma_f32_16x16x32_bf16(
                    af[mf], bfr[nf], acc[mf][nf], 0, 0, 0);
        __builtin_amdgcn_s_setprio(0);
        __syncthreads();
    }

    const float QSCALE = 0.125f * 1.44269504088896f;   // exp2-domain scores
    #pragma unroll
    for (int mf = 0; mf < 4; ++mf) {
        const int o3b = m0 + wr * 64 + mf * 16 + 4 * lg;
        float bv[4];
        #pragma unroll
        for (int i = 0; i < 4; ++i) bv[i] = bias[o3b + i];
        #pragma unroll
        for (int nf = 0; nf < 4; ++nf) {
            const int s = n0 + wc * 64 + nf * 16 + lr;
            if (m0 < 512) {          // Q -> Qt[b][h][s][d], scaled
                int h = o3b >> 6, d = o3b & 63;
                u16x4 pk;
                #pragma unroll
                for (int i = 0; i < 4; ++i)
                    pk[i] = (u16)f2bf((acc[mf][nf][i] + bv[i]) * QSCALE);
                *(u16x4*)(Qt + (((size_t)bi * 8 + h) * S + s) * 64 + d) = pk;
            } else if (m0 < 1024) {  // K -> Kt[b][h][s][d]
                int ok = o3b - 512;
                int h = ok >> 6, d = ok & 63;
                u16x4 pk;
                #pragma unroll
                for (int i = 0; i < 4; ++i) pk[i] = (u16)f2bf(acc[mf][nf][i] + bv[i]);
                *(u16x4*)(Kt + (((size_t)bi * 8 + h) * S + s) * 64 + d) = pk;
            } else {                 // V -> Vn[b][c][s]
                int ov = o3b - 1024;
                #pragma unroll
                for (int i = 0; i < 4; ++i)
                    Vn[(size_t)(bi * C + ov + i) * S + s] = (u16)f2bf(acc[mf][nf][i] + bv[i]);
            }
        }
    }
}

// Attention, swapped operands, exp2 domain. grid (64 bh, 8 qb), 512 threads
// = 8 waves, 128 queries/block. K/V double-buffered via global_load_lds with
// XOR-swizzle; per-wave P buffer; defer-max (THR=8, log2 domain); setprio.
__global__ __launch_bounds__(512) void attn_mfma(
    const u16* __restrict__ Qt, const u16* __restrict__ Kt,
    const u16* __restrict__ Vn, u16* __restrict__ At)
{
    const int bh = blockIdx.x, qb = blockIdx.y;
    const int bi = bh >> 3, h = bh & 7;
    const int tid = threadIdx.x, wave = tid >> 6, lane = tid & 63;
    const int lr = lane & 15, lg = lane >> 4;
    const int q0 = qb * 128 + wave * 16;

    const u16* qt = Qt + ((size_t)bi * 8 + h) * S * 64;
    const u16* kp = Kt + ((size_t)bi * 8 + h) * S * 64;
    const u16* vp = Vn + (size_t)(bi * C + h * 64) * S;

    __shared__ __attribute__((aligned(16))) short Ks[2][4096];   // [64k][64d] swz
    __shared__ __attribute__((aligned(16))) short Vs[2][4096];   // [64d][64k] swz
    __shared__ __attribute__((aligned(16))) short Pw[8][16][64]; // per-wave P, swz

    bf16x8 aq0 = *(const bf16x8*)(qt + (size_t)(q0 + lr) * 64 + lg * 8);
    bf16x8 aq1 = *(const bf16x8*)(qt + (size_t)(q0 + lr) * 64 + 32 + lg * 8);

    float mrun = -1e30f, lrun = 0.f;
    f32x4 acc[4];
    #pragma unroll
    for (int df = 0; df < 4; ++df) acc[df] = (f32x4){0.f, 0.f, 0.f, 0.f};

    // one K-load + one V-load per thread per tile (512 thr x 16B = 8KB each)
    auto STAGE = [&](int buf, int kt0) {
        int r = tid >> 3, cs = (tid & 7) ^ (r & 7);
        short* ldsK = &Ks[buf][(wave << 6) * 8];
        short* ldsV = &Vs[buf][(wave << 6) * 8];
        gload_lds16(kp + (size_t)(kt0 + r) * 64 + cs * 8, ldsK);
        gload_lds16(vp + (size_t)r * S + kt0 + cs * 8, ldsV);
    };

    unsigned* pwb = (unsigned*)&Pw[wave][0][0];
    const int rsw = lr & 7;

    STAGE(0, 0);
    __syncthreads();

    for (int kt = 0; kt < 16; ++kt) {
        const int cur = kt & 1;
        if (kt < 15) STAGE(cur ^ 1, (kt + 1) * 64);

        // ---- scores (swapped): sc[kf][i] = S^T[k=kf*16+4lg+i][q=lr] ----
        f32x4 sc[4];
        __builtin_amdgcn_s_setprio(1);
        #pragma unroll
        for (int kf = 0; kf < 4; ++kf) {
            int rK = kf * 16 + lr;
            bf16x8 b0 = *(bf16x8*)&Ks[cur][rK * 64 + (lg ^ (rK & 7)) * 8];
            bf16x8 b1 = *(bf16x8*)&Ks[cur][rK * 64 + ((lg + 4) ^ (rK & 7)) * 8];
            f32x4 z = (f32x4){0.f, 0.f, 0.f, 0.f};
            z = __builtin_amdgcn_mfma_f32_16x16x32_bf16(b0, aq0, z, 0, 0, 0);
            sc[kf] = __builtin_amdgcn_mfma_f32_16x16x32_bf16(b1, aq1, z, 0, 0, 0);
        }
        __builtin_amdgcn_s_setprio(0);

        // ---- softmax (log2 domain), row q = lr lane-local ----
        float tmax = sc[0][0];
        #pragma unroll
        for (int kf = 0; kf < 4; ++kf)
            #pragma unroll
            for (int i = 0; i < 4; ++i) tmax = fmaxf(tmax, sc[kf][i]);
        tmax = fmaxf(tmax, __shfl_xor(tmax, 16));
        tmax = fmaxf(tmax, __shfl_xor(tmax, 32));

        // defer-max: only rescale when the wave's max grew past THR=8
        if (!__all(tmax <= mrun + 8.f)) {
            float mnew = fmaxf(mrun, tmax);
            float fac = __builtin_amdgcn_exp2f(mrun - mnew);
            mrun = mnew;
            lrun *= fac;
            #pragma unroll
            for (int df = 0; df < 4; ++df) acc[df] *= fac;
        }

        float sum = 0.f;
        #pragma unroll
        for (int kf = 0; kf < 4; ++kf)
            #pragma unroll
            for (int i = 0; i < 4; ++i) {
                sc[kf][i] = __builtin_amdgcn_exp2f(sc[kf][i] - mrun);
                sum += sc[kf][i];
            }

        // ---- P pack + swizzled write (4x ds_write_b64) ----
        #pragma unroll
        for (int kf = 0; kf < 4; ++kf) {
            unsigned p0 = cvt_pk_bf16(sc[kf][0], sc[kf][1]);
            unsigned p1 = cvt_pk_bf16(sc[kf][2], sc[kf][3]);
            int c0 = kf * 8 + 2 * lg;                    // u32 col, even
            int idx = lr * 32 + ((c0 >> 2) ^ rsw) * 4 + (c0 & 3);
            *(u32x2*)&pwb[idx] = (u32x2){p0, p1};
        }

        sum += __shfl_xor(sum, 16);
        sum += __shfl_xor(sum, 32);
        lrun += sum;

        // ---- PV (swapped): B = P[q=lr][k chunk], A = V[d][k chunk] ----
        bf16x8 pb0 = *(bf16x8*)&Pw[wave][lr][(lg ^ rsw) * 8];
        bf16x8 pb1 = *(bf16x8*)&Pw[wave][lr][((4 + lg) ^ rsw) * 8];
        __builtin_amdgcn_s_setprio(1);
        #pragma unroll
        for (int df = 0; df < 4; ++df) {
            int rV = df * 16 + lr;
            bf16x8 v0 = *(bf16x8*)&Vs[cur][rV * 64 + (lg ^ (rV & 7)) * 8];
            bf16x8 v1 = *(bf16x8*)&Vs[cur][rV * 64 + ((lg + 4) ^ (rV & 7)) * 8];
            acc[df] = __builtin_amdgcn_mfma_f32_16x16x32_bf16(v0, pb0, acc[df], 0, 0, 0);
            acc[df] = __builtin_amdgcn_mfma_f32_16x16x32_bf16(v1, pb1, acc[df], 0, 0, 0);
        }
        __builtin_amdgcn_s_setprio(0);
        __syncthreads();   // drains next-tile stage loads; guards buffer reuse
    }

    // ---- epilogue: lane q = q0+lr, d = df*16 + 4*lg + i ----
    float linv = 1.f / lrun;
    #pragma unroll
    for (int df = 0; df < 4; ++df) {
        u16x4 pk;
        #pragma unroll
        for (int i = 0; i < 4; ++i) pk[i] = (u16)f2bf(acc[df][i] * linv);
        *(u16x4*)(At + ((size_t)bi * S + q0 + lr) * C + h * 64 + df * 16 + 4 * lg) = pk;
    }
}

// proj: A=Wp[512][512] x Bt=attn_t[s][c] + bias + residual -> fp32 out
__global__ __launch_bounds__(256) void proj_mfma(
    const u16* __restrict__ A, const u16* __restrict__ Bt,
    const float* __restrict__ bias, const float* __restrict__ Xres,
    float* __restrict__ out)
{
    const int n0 = blockIdx.x * 128, m0 = blockIdx.y * 128;
    const int bi = blockIdx.z;
    const int tid = threadIdx.x, wave = tid >> 6, lane = tid & 63;
    const int lr = lane & 15, lg = lane >> 4;
    const int wr = wave >> 1, wc = wave & 1;

    __shared__ __attribute__((aligned(16))) short As[2][8][512];
    __shared__ __attribute__((aligned(16))) short Bs[2][8][512];

    f32x4 acc[4][4];
    #pragma unroll
    for (int i = 0; i < 4; ++i)
        #pragma unroll
        for (int j = 0; j < 4; ++j) acc[i][j] = (f32x4){0.f, 0.f, 0.f, 0.f};

    const u16* aP0 = A + (size_t)(m0 + wave * 16 + lr) * C + lg * 8;
    const u16* aP1 = A + (size_t)(m0 + (wave + 4) * 16 + lr) * C + lg * 8;
    const u16* bP0 = Bt + (size_t)bi * S * C + (size_t)(n0 + wave * 16 + lr) * C + lg * 8;
    const u16* bP1 = Bt + (size_t)bi * S * C + (size_t)(n0 + (wave + 4) * 16 + lr) * C + lg * 8;

    auto STAGE = [&](int buf, int k0) {
        gload_lds16(aP0 + k0, &As[buf][wave][0]);
        gload_lds16(aP1 + k0, &As[buf][wave + 4][0]);
        gload_lds16(bP0 + k0, &Bs[buf][wave][0]);
        gload_lds16(bP1 + k0, &Bs[buf][wave + 4][0]);
    };

    STAGE(0, 0);
    __syncthreads();

    for (int kt = 0; kt < 16; ++kt) {
        const int cur = kt & 1;
        if (kt < 15) STAGE(cur ^ 1, (kt + 1) * 32);
        bf16x8 af[4], bfr[4];
        #pragma unroll
        for (int mf = 0; mf < 4; ++mf) af[mf] = *(bf16x8*)&As[cur][wr * 4 + mf][lane * 8];
        #pragma unroll
        for (int nf = 0; nf < 4; ++nf) bfr[nf] = *(bf16x8*)&Bs[cur][wc * 4 + nf][lane * 8];
        __builtin_amdgcn_s_setprio(1);
        #pragma unroll
        for (int mf = 0; mf < 4; ++mf)
            #pragma unroll
            for (int nf = 0; nf < 4; ++nf)
                acc[mf][nf] = __builtin_amdgcn_mfma_f32_16x16x32_bf16(
                    af[mf], bfr[nf], acc[mf][nf], 0, 0, 0);
        __builtin_amdgcn_s_setprio(0);
        __syncthreads();
    }

    #pragma unroll
    for (int mf = 0; mf < 4; ++mf) {
        const int ob = m0 + wr * 64 + mf * 16 + 4 * lg;
        float bv[4];
        #pragma unroll
        for (int i = 0; i < 4; ++i) bv[i] = bias[ob + i];
        #pragma unroll
        for (int nf = 0; nf < 4; ++nf) {
            const int s = n0 + wc * 64 + nf * 16 + lr;
            #pragma unroll
            for (int i = 0; i < 4; ++i) {
                size_t oi = ((size_t)bi * C + ob + i) * S + s;
                out[oi] = acc[mf][nf][i] + bv[i] + Xres[oi];
            }
        }
    }
}

extern "C" void kernel_launch(void* const* d_in, const int* in_sizes, int n_in,
                              void* d_out, int out_size, void* d_ws, size_t ws_size,
                              hipStream_t stream) {
    const float* X      = (const float*)d_in[0];
    const float* norm_w = (const float*)d_in[1];
    const float* norm_b = (const float*)d_in[2];
    const float* qkv_w  = (const float*)d_in[3];
    const float* qkv_b  = (const float*)d_in[4];
    const float* proj_w = (const float*)d_in[5];
    const float* proj_b = (const float*)d_in[6];
    float* out = (float*)d_out;

    float* scaleA = (float*)d_ws;              // 4096 f
    float* shiftB = scaleA + 4096;             // 4096 f
    u16* Wq_bf = (u16*)(shiftB + 4096);        // 1536*512
    u16* Wp_bf = Wq_bf + 786432;               // 512*512
    u16* Xn_t  = Wp_bf + 262144;               // 8*1024*512
    u16* Qt    = Xn_t + 4194304;               // 8*8*1024*64
    u16* Kt    = Qt + 4194304;
    u16* Vn    = Kt + 4194304;                 // 8*512*1024
    u16* At    = Vn + 4194304;                 // 8*1024*512

    gn_stats<<<dim3(BATCH * 32), 256, 0, stream>>>(X, norm_w, norm_b, scaleA, shiftB);
    wconv<<<dim3(384), 256, 0, stream>>>(qkv_w, Wq_bf, 98304);
    wconv<<<dim3(128), 256, 0, stream>>>(proj_w, Wp_bf, 32768);
    xnt_kernel<<<dim3(S / 64, C / 64, BATCH), 256, 0, stream>>>(X, scaleA, shiftB, Xn_t);
    qkv_mfma<<<dim3(S / 128, OC3 / 128, BATCH), 256, 0, stream>>>(
        Wq_bf, Xn_t, qkv_b, Qt, Kt, Vn);
    attn_mfma<<<dim3(64, S / 128), 512, 0, stream>>>(Qt, Kt, Vn, At);
    proj_mfma<<<dim3(S / 128, C / 128, BATCH), 256, 0, stream>>>(
        Wp_bf, At, proj_b, X, out);
}

// Round 7
// 103.182 us; speedup vs baseline: 9.8741x; 1.0269x over previous
//
#include <hip/hip_runtime.h>
#include <hip/hip_bf16.h>

// AttentionBlock  B=8, C=512, H=W=32 (S=1024), heads=8, hd=64, groups=32
// Round 7: gn_stats+xnt fused into gnx (X read once, LDS-resident group tile);
// qkv V-epilogue via swizzled LDS transpose (64 scalar stores -> 8 b128);
// wconv merged. attn/proj unchanged from round 6.

#define BATCH 8
#define C 512
#define S 1024
#define HEADS 8
#define OC3 1536

typedef short bf16x8 __attribute__((ext_vector_type(8)));
typedef float f32x4 __attribute__((ext_vector_type(4)));
typedef unsigned u32x2 __attribute__((ext_vector_type(2)));
typedef unsigned short u16;
typedef unsigned short u16x4 __attribute__((ext_vector_type(4)));

__device__ inline short f2bf(float x) {
    union { float f; unsigned u; } v; v.f = x;
    unsigned r = v.u + 0x7fffu + ((v.u >> 16) & 1u);   // RNE
    return (short)(r >> 16);
}

__device__ inline unsigned cvt_pk_bf16(float lo, float hi) {
    unsigned r;
    asm("v_cvt_pk_bf16_f32 %0, %1, %2" : "=v"(r) : "v"(lo), "v"(hi));
    return r;
}

__device__ inline void gload_lds16(const u16* g, short* l) {
    __builtin_amdgcn_global_load_lds(
        (const __attribute__((address_space(1))) unsigned int*)g,
        (__attribute__((address_space(3))) unsigned int*)l, 16, 0, 0);
}

// Fused GroupNorm stats + affine + transpose: X[b][c][s] fp32 -> Xn_t[b][s][c] bf16.
// Block = (b, g): 16 channels x 1024 spatial staged in LDS fp32; X read ONCE.
__global__ __launch_bounds__(512) void gnx_kernel(
    const float* __restrict__ X, const float* __restrict__ nw,
    const float* __restrict__ nb, u16* __restrict__ Xn_t)
{
    const int blk = blockIdx.x;
    const int bi = blk >> 5, g = blk & 31;
    const int tid = threadIdx.x;
    __shared__ __attribute__((aligned(16))) float T[16][1032];   // pad 8 floats
    __shared__ float red[16];
    __shared__ float sh_mr[2];

    const float* Xg = X + ((size_t)bi * C + g * 16) * S;   // 16384 contiguous
    float s = 0.f, ss = 0.f;
    #pragma unroll
    for (int r = 0; r < 8; ++r) {
        int idx4 = r * 512 + tid;                 // 0..4095 float4s
        f32x4 v = *(const f32x4*)(Xg + (size_t)idx4 * 4);
        int c = idx4 >> 8, sp = (idx4 * 4) & 1023;
        *(f32x4*)&T[c][sp] = v;
        s  += v[0] + v[1] + v[2] + v[3];
        ss += v[0]*v[0] + v[1]*v[1] + v[2]*v[2] + v[3]*v[3];
    }
    #pragma unroll
    for (int m = 1; m <= 32; m <<= 1) {
        s += __shfl_xor(s, m); ss += __shfl_xor(ss, m);
    }
    if ((tid & 63) == 0) { red[tid >> 6] = s; red[8 + (tid >> 6)] = ss; }
    __syncthreads();
    if (tid == 0) {
        float S1 = 0.f, S2 = 0.f;
        #pragma unroll
        for (int w = 0; w < 8; ++w) { S1 += red[w]; S2 += red[8 + w]; }
        float mean = S1 * (1.f / 16384.f);
        float var  = S2 * (1.f / 16384.f) - mean * mean;
        sh_mr[0] = mean; sh_mr[1] = rsqrtf(var + 1e-5f);
    }
    __syncthreads();
    const float mean = sh_mr[0], rstd = sh_mr[1];
    float rw[16], sb[16];
    #pragma unroll
    for (int c = 0; c < 16; ++c) {
        float w = nw[g * 16 + c], b = nb[g * 16 + c];
        rw[c] = rstd * w;
        sb[c] = b - mean * rw[c];
    }
    #pragma unroll
    for (int r = 0; r < 2; ++r) {
        int sp = r * 512 + tid;
        bf16x8 o0, o1;
        #pragma unroll
        for (int c = 0; c < 8; ++c) o0[c] = f2bf(T[c][sp] * rw[c] + sb[c]);
        #pragma unroll
        for (int c = 0; c < 8; ++c) o1[c] = f2bf(T[8 + c][sp] * rw[8 + c] + sb[8 + c]);
        u16* dst = Xn_t + ((size_t)bi * S + sp) * C + g * 16;
        *(bf16x8*)dst = o0;
        *(bf16x8*)(dst + 8) = o1;
    }
}

// Both weight conversions in one launch. grid 512 x 256 covers 131072 rows of 8.
__global__ __launch_bounds__(256) void wconv2(
    const float* __restrict__ wq, const float* __restrict__ wp,
    u16* __restrict__ oq, u16* __restrict__ op)
{
    int i = blockIdx.x * 256 + threadIdx.x;
    const float* w; u16* o; int j;
    if (i < 98304) { w = wq; o = oq; j = i; }
    else           { w = wp; o = op; j = i - 98304; }
    f32x4 a = *(const f32x4*)(w + (size_t)j * 8);
    f32x4 b = *(const f32x4*)(w + (size_t)j * 8 + 4);
    bf16x8 r;
    #pragma unroll
    for (int k = 0; k < 4; ++k) { r[k] = f2bf(a[k]); r[4 + k] = f2bf(b[k]); }
    *(bf16x8*)(o + (size_t)j * 8) = r;
}

// GEMM: A[M][K] bf16 x Bt[N][K] bf16. 128x128 tile, BK=32, 4 waves,
// double-buffered unified LDS (A = row[0..511], B = row[512..1023]),
// STAGE(next) before compute, 1 barrier/iter.
// Q epilogue folds 0.125*log2(e); V epilogue via swizzled LDS transpose.
__global__ __launch_bounds__(256) void qkv_mfma(
    const u16* __restrict__ A, const u16* __restrict__ Bt,
    const float* __restrict__ bias,
    u16* __restrict__ Qt, u16* __restrict__ Kt, u16* __restrict__ Vn)
{
    const int n0 = blockIdx.x * 128, m0 = blockIdx.y * 128;
    const int bi = blockIdx.z;
    const int tid = threadIdx.x, wave = tid >> 6, lane = tid & 63;
    const int lr = lane & 15, lg = lane >> 4;
    const int wr = wave >> 1, wc = wave & 1;

    __shared__ __attribute__((aligned(16))) short SM[2][8][1024];

    f32x4 acc[4][4];
    #pragma unroll
    for (int i = 0; i < 4; ++i)
        #pragma unroll
        for (int j = 0; j < 4; ++j) acc[i][j] = (f32x4){0.f, 0.f, 0.f, 0.f};

    const u16* aP0 = A + (size_t)(m0 + wave * 16 + lr) * C + lg * 8;
    const u16* aP1 = A + (size_t)(m0 + (wave + 4) * 16 + lr) * C + lg * 8;
    const u16* bP0 = Bt + (size_t)bi * S * C + (size_t)(n0 + wave * 16 + lr) * C + lg * 8;
    const u16* bP1 = Bt + (size_t)bi * S * C + (size_t)(n0 + (wave + 4) * 16 + lr) * C + lg * 8;

    auto STAGE = [&](int buf, int k0) {
        gload_lds16(aP0 + k0, &SM[buf][wave][0]);
        gload_lds16(aP1 + k0, &SM[buf][wave + 4][0]);
        gload_lds16(bP0 + k0, &SM[buf][wave][512]);
        gload_lds16(bP1 + k0, &SM[buf][wave + 4][512]);
    };

    STAGE(0, 0);
    __syncthreads();

    for (int kt = 0; kt < 16; ++kt) {
        const int cur = kt & 1;
        if (kt < 15) STAGE(cur ^ 1, (kt + 1) * 32);
        bf16x8 af[4], bfr[4];
        #pragma unroll
        for (int mf = 0; mf < 4; ++mf) af[mf] = *(bf16x8*)&SM[cur][wr * 4 + mf][lane * 8];
        #pragma unroll
        for (int nf = 0; nf < 4; ++nf) bfr[nf] = *(bf16x8*)&SM[cur][wc * 4 + nf][512 + lane * 8];
        __builtin_amdgcn_s_setprio(1);
        #pragma unroll
        for (int mf = 0; mf < 4; ++mf)
            #pragma unroll
            for (int nf = 0; nf < 4; ++nf)
                acc[mf][nf] = __builtin_amdgcn_mfma_f32_16x16x32_bf16(
                    af[mf], bfr[nf], acc[mf][nf], 0, 0, 0);
        __builtin_amdgcn_s_setprio(0);
        __syncthreads();
    }

    const float QSCALE = 0.125f * 1.44269504088896f;   // exp2-domain scores
    if (m0 < 1024) {
        #pragma unroll
        for (int mf = 0; mf < 4; ++mf) {
            const int o3b = m0 + wr * 64 + mf * 16 + 4 * lg;
            float bv[4];
            #pragma unroll
            for (int i = 0; i < 4; ++i) bv[i] = bias[o3b + i];
            #pragma unroll
            for (int nf = 0; nf < 4; ++nf) {
                const int s = n0 + wc * 64 + nf * 16 + lr;
                if (m0 < 512) {          // Q -> Qt[b][h][s][d], scaled
                    int h = o3b >> 6, d = o3b & 63;
                    u16x4 pk;
                    #pragma unroll
                    for (int i = 0; i < 4; ++i)
                        pk[i] = (u16)f2bf((acc[mf][nf][i] + bv[i]) * QSCALE);
                    *(u16x4*)(Qt + (((size_t)bi * 8 + h) * S + s) * 64 + d) = pk;
                } else {                 // K -> Kt[b][h][s][d]
                    int ok = o3b - 512;
                    int h = ok >> 6, d = ok & 63;
                    u16x4 pk;
                    #pragma unroll
                    for (int i = 0; i < 4; ++i) pk[i] = (u16)f2bf(acc[mf][nf][i] + bv[i]);
                    *(u16x4*)(Kt + (((size_t)bi * 8 + h) * S + s) * 64 + d) = pk;
                }
            }
        }
    } else {
        // V: transpose in LDS (post-loop, buffers free) -> coalesced [d][s] stores
        short* Ts = &SM[0][0][0];   // [128][128] bf16, XOR-swizzled columns
        #pragma unroll
        for (int mf = 0; mf < 4; ++mf) {
            const int orl = wr * 64 + mf * 16 + 4 * lg;
            float bv[4];
            #pragma unroll
            for (int i = 0; i < 4; ++i) bv[i] = bias[m0 + orl + i];
            #pragma unroll
            for (int nf = 0; nf < 4; ++nf) {
                const int srl = wc * 64 + nf * 16 + lr;
                #pragma unroll
                for (int i = 0; i < 4; ++i) {
                    int o = orl + i;
                    Ts[o * 128 + (srl ^ ((o & 7) << 3))] =
                        (short)f2bf(acc[mf][nf][i] + bv[i]);
                }
            }
        }
        __syncthreads();
        const int o = tid >> 1, half = (tid & 1) * 64;
        const int x = (o & 7) << 3;
        const int ov0 = m0 - 1024;
        u16* vdst = Vn + (size_t)(bi * C + ov0 + o) * S + n0 + half;
        #pragma unroll
        for (int c = 0; c < 8; ++c)
            *(bf16x8*)(vdst + 8 * c) = *(bf16x8*)&Ts[o * 128 + ((half + 8 * c) ^ x)];
    }
}

// Attention, swapped operands, exp2 domain. grid (64 bh, 8 qb), 512 threads
// = 8 waves, 128 queries/block. K/V double-buffered via global_load_lds with
// XOR-swizzle; per-wave P buffer; defer-max (THR=8, log2 domain); setprio.
__global__ __launch_bounds__(512) void attn_mfma(
    const u16* __restrict__ Qt, const u16* __restrict__ Kt,
    const u16* __restrict__ Vn, u16* __restrict__ At)
{
    const int bh = blockIdx.x, qb = blockIdx.y;
    const int bi = bh >> 3, h = bh & 7;
    const int tid = threadIdx.x, wave = tid >> 6, lane = tid & 63;
    const int lr = lane & 15, lg = lane >> 4;
    const int q0 = qb * 128 + wave * 16;

    const u16* qt = Qt + ((size_t)bi * 8 + h) * S * 64;
    const u16* kp = Kt + ((size_t)bi * 8 + h) * S * 64;
    const u16* vp = Vn + (size_t)(bi * C + h * 64) * S;

    __shared__ __attribute__((aligned(16))) short Ks[2][4096];   // [64k][64d] swz
    __shared__ __attribute__((aligned(16))) short Vs[2][4096];   // [64d][64k] swz
    __shared__ __attribute__((aligned(16))) short Pw[8][16][64]; // per-wave P, swz

    bf16x8 aq0 = *(const bf16x8*)(qt + (size_t)(q0 + lr) * 64 + lg * 8);
    bf16x8 aq1 = *(const bf16x8*)(qt + (size_t)(q0 + lr) * 64 + 32 + lg * 8);

    float mrun = -1e30f, lrun = 0.f;
    f32x4 acc[4];
    #pragma unroll
    for (int df = 0; df < 4; ++df) acc[df] = (f32x4){0.f, 0.f, 0.f, 0.f};

    auto STAGE = [&](int buf, int kt0) {
        int r = tid >> 3, cs = (tid & 7) ^ (r & 7);
        short* ldsK = &Ks[buf][(wave << 6) * 8];
        short* ldsV = &Vs[buf][(wave << 6) * 8];
        gload_lds16(kp + (size_t)(kt0 + r) * 64 + cs * 8, ldsK);
        gload_lds16(vp + (size_t)r * S + kt0 + cs * 8, ldsV);
    };

    unsigned* pwb = (unsigned*)&Pw[wave][0][0];
    const int rsw = lr & 7;

    STAGE(0, 0);
    __syncthreads();

    for (int kt = 0; kt < 16; ++kt) {
        const int cur = kt & 1;
        if (kt < 15) STAGE(cur ^ 1, (kt + 1) * 64);

        // ---- scores (swapped): sc[kf][i] = S^T[k=kf*16+4lg+i][q=lr] ----
        f32x4 sc[4];
        __builtin_amdgcn_s_setprio(1);
        #pragma unroll
        for (int kf = 0; kf < 4; ++kf) {
            int rK = kf * 16 + lr;
            bf16x8 b0 = *(bf16x8*)&Ks[cur][rK * 64 + (lg ^ (rK & 7)) * 8];
            bf16x8 b1 = *(bf16x8*)&Ks[cur][rK * 64 + ((lg + 4) ^ (rK & 7)) * 8];
            f32x4 z = (f32x4){0.f, 0.f, 0.f, 0.f};
            z = __builtin_amdgcn_mfma_f32_16x16x32_bf16(b0, aq0, z, 0, 0, 0);
            sc[kf] = __builtin_amdgcn_mfma_f32_16x16x32_bf16(b1, aq1, z, 0, 0, 0);
        }
        __builtin_amdgcn_s_setprio(0);

        // ---- softmax (log2 domain), row q = lr lane-local ----
        float tmax = sc[0][0];
        #pragma unroll
        for (int kf = 0; kf < 4; ++kf)
            #pragma unroll
            for (int i = 0; i < 4; ++i) tmax = fmaxf(tmax, sc[kf][i]);
        tmax = fmaxf(tmax, __shfl_xor(tmax, 16));
        tmax = fmaxf(tmax, __shfl_xor(tmax, 32));

        if (!__all(tmax <= mrun + 8.f)) {
            float mnew = fmaxf(mrun, tmax);
            float fac = __builtin_amdgcn_exp2f(mrun - mnew);
            mrun = mnew;
            lrun *= fac;
            #pragma unroll
            for (int df = 0; df < 4; ++df) acc[df] *= fac;
        }

        float sum = 0.f;
        #pragma unroll
        for (int kf = 0; kf < 4; ++kf)
            #pragma unroll
            for (int i = 0; i < 4; ++i) {
                sc[kf][i] = __builtin_amdgcn_exp2f(sc[kf][i] - mrun);
                sum += sc[kf][i];
            }

        // ---- P pack + swizzled write (4x ds_write_b64) ----
        #pragma unroll
        for (int kf = 0; kf < 4; ++kf) {
            unsigned p0 = cvt_pk_bf16(sc[kf][0], sc[kf][1]);
            unsigned p1 = cvt_pk_bf16(sc[kf][2], sc[kf][3]);
            int c0 = kf * 8 + 2 * lg;                    // u32 col, even
            int idx = lr * 32 + ((c0 >> 2) ^ rsw) * 4 + (c0 & 3);
            *(u32x2*)&pwb[idx] = (u32x2){p0, p1};
        }

        sum += __shfl_xor(sum, 16);
        sum += __shfl_xor(sum, 32);
        lrun += sum;

        // ---- PV (swapped): B = P[q=lr][k chunk], A = V[d][k chunk] ----
        bf16x8 pb0 = *(bf16x8*)&Pw[wave][lr][(lg ^ rsw) * 8];
        bf16x8 pb1 = *(bf16x8*)&Pw[wave][lr][((4 + lg) ^ rsw) * 8];
        __builtin_amdgcn_s_setprio(1);
        #pragma unroll
        for (int df = 0; df < 4; ++df) {
            int rV = df * 16 + lr;
            bf16x8 v0 = *(bf16x8*)&Vs[cur][rV * 64 + (lg ^ (rV & 7)) * 8];
            bf16x8 v1 = *(bf16x8*)&Vs[cur][rV * 64 + ((lg + 4) ^ (rV & 7)) * 8];
            acc[df] = __builtin_amdgcn_mfma_f32_16x16x32_bf16(v0, pb0, acc[df], 0, 0, 0);
            acc[df] = __builtin_amdgcn_mfma_f32_16x16x32_bf16(v1, pb1, acc[df], 0, 0, 0);
        }
        __builtin_amdgcn_s_setprio(0);
        __syncthreads();   // drains next-tile stage loads; guards buffer reuse
    }

    float linv = 1.f / lrun;
    #pragma unroll
    for (int df = 0; df < 4; ++df) {
        u16x4 pk;
        #pragma unroll
        for (int i = 0; i < 4; ++i) pk[i] = (u16)f2bf(acc[df][i] * linv);
        *(u16x4*)(At + ((size_t)bi * S + q0 + lr) * C + h * 64 + df * 16 + 4 * lg) = pk;
    }
}

// proj: A=Wp[512][512] x Bt=attn_t[s][c] + bias + residual -> fp32 out
__global__ __launch_bounds__(256) void proj_mfma(
    const u16* __restrict__ A, const u16* __restrict__ Bt,
    const float* __restrict__ bias, const float* __restrict__ Xres,
    float* __restrict__ out)
{
    const int n0 = blockIdx.x * 128, m0 = blockIdx.y * 128;
    const int bi = blockIdx.z;
    const int tid = threadIdx.x, wave = tid >> 6, lane = tid & 63;
    const int lr = lane & 15, lg = lane >> 4;
    const int wr = wave >> 1, wc = wave & 1;

    __shared__ __attribute__((aligned(16))) short SM[2][8][1024];

    f32x4 acc[4][4];
    #pragma unroll
    for (int i = 0; i < 4; ++i)
        #pragma unroll
        for (int j = 0; j < 4; ++j) acc[i][j] = (f32x4){0.f, 0.f, 0.f, 0.f};

    const u16* aP0 = A + (size_t)(m0 + wave * 16 + lr) * C + lg * 8;
    const u16* aP1 = A + (size_t)(m0 + (wave + 4) * 16 + lr) * C + lg * 8;
    const u16* bP0 = Bt + (size_t)bi * S * C + (size_t)(n0 + wave * 16 + lr) * C + lg * 8;
    const u16* bP1 = Bt + (size_t)bi * S * C + (size_t)(n0 + (wave + 4) * 16 + lr) * C + lg * 8;

    auto STAGE = [&](int buf, int k0) {
        gload_lds16(aP0 + k0, &SM[buf][wave][0]);
        gload_lds16(aP1 + k0, &SM[buf][wave + 4][0]);
        gload_lds16(bP0 + k0, &SM[buf][wave][512]);
        gload_lds16(bP1 + k0, &SM[buf][wave + 4][512]);
    };

    STAGE(0, 0);
    __syncthreads();

    for (int kt = 0; kt < 16; ++kt) {
        const int cur = kt & 1;
        if (kt < 15) STAGE(cur ^ 1, (kt + 1) * 32);
        bf16x8 af[4], bfr[4];
        #pragma unroll
        for (int mf = 0; mf < 4; ++mf) af[mf] = *(bf16x8*)&SM[cur][wr * 4 + mf][lane * 8];
        #pragma unroll
        for (int nf = 0; nf < 4; ++nf) bfr[nf] = *(bf16x8*)&SM[cur][wc * 4 + nf][512 + lane * 8];
        __builtin_amdgcn_s_setprio(1);
        #pragma unroll
        for (int mf = 0; mf < 4; ++mf)
            #pragma unroll
            for (int nf = 0; nf < 4; ++nf)
                acc[mf][nf] = __builtin_amdgcn_mfma_f32_16x16x32_bf16(
                    af[mf], bfr[nf], acc[mf][nf], 0, 0, 0);
        __builtin_amdgcn_s_setprio(0);
        __syncthreads();
    }

    #pragma unroll
    for (int mf = 0; mf < 4; ++mf) {
        const int ob = m0 + wr * 64 + mf * 16 + 4 * lg;
        float bv[4];
        #pragma unroll
        for (int i = 0; i < 4; ++i) bv[i] = bias[ob + i];
        #pragma unroll
        for (int nf = 0; nf < 4; ++nf) {
            const int s = n0 + wc * 64 + nf * 16 + lr;
            #pragma unroll
            for (int i = 0; i < 4; ++i) {
                size_t oi = ((size_t)bi * C + ob + i) * S + s;
                out[oi] = acc[mf][nf][i] + bv[i] + Xres[oi];
            }
        }
    }
}

extern "C" void kernel_launch(void* const* d_in, const int* in_sizes, int n_in,
                              void* d_out, int out_size, void* d_ws, size_t ws_size,
                              hipStream_t stream) {
    const float* X      = (const float*)d_in[0];
    const float* norm_w = (const float*)d_in[1];
    const float* norm_b = (const float*)d_in[2];
    const float* qkv_w  = (const float*)d_in[3];
    const float* qkv_b  = (const float*)d_in[4];
    const float* proj_w = (const float*)d_in[5];
    const float* proj_b = (const float*)d_in[6];
    float* out = (float*)d_out;

    u16* Wq_bf = (u16*)d_ws;                   // 1536*512
    u16* Wp_bf = Wq_bf + 786432;               // 512*512
    u16* Xn_t  = Wp_bf + 262144;               // 8*1024*512
    u16* Qt    = Xn_t + 4194304;               // 8*8*1024*64
    u16* Kt    = Qt + 4194304;
    u16* Vn    = Kt + 4194304;                 // 8*512*1024
    u16* At    = Vn + 4194304;                 // 8*1024*512

    gnx_kernel<<<dim3(BATCH * 32), 512, 0, stream>>>(X, norm_w, norm_b, Xn_t);
    wconv2<<<dim3(512), 256, 0, stream>>>(qkv_w, proj_w, Wq_bf, Wp_bf);
    qkv_mfma<<<dim3(S / 128, OC3 / 128, BATCH), 256, 0, stream>>>(
        Wq_bf, Xn_t, qkv_b, Qt, Kt, Vn);
    attn_mfma<<<dim3(64, S / 128), 512, 0, stream>>>(Qt, Kt, Vn, At);
    proj_mfma<<<dim3(S / 128, C / 128, BATCH), 256, 0, stream>>>(
        Wp_bf, At, proj_b, X, out);
}

// Round 8
// 88.224 us; speedup vs baseline: 11.5481x; 1.1695x over previous
//
#include <hip/hip_runtime.h>
#include <hip/hip_bf16.h>

// AttentionBlock  B=8, C=512, H=W=32 (S=1024), heads=8, hd=64, groups=32
// Round 8: qkv/proj GEMMs -> 3-buffer counted-vmcnt pipeline (T3/T4):
// STAGE(kt+2) issued at top of iter, s_waitcnt vmcnt(4) + raw s_barrier at
// bottom (loads stay in flight across the barrier). gnx/attn unchanged.

#define BATCH 8
#define C 512
#define S 1024
#define HEADS 8
#define OC3 1536

typedef short bf16x8 __attribute__((ext_vector_type(8)));
typedef float f32x4 __attribute__((ext_vector_type(4)));
typedef unsigned u32x2 __attribute__((ext_vector_type(2)));
typedef unsigned short u16;
typedef unsigned short u16x4 __attribute__((ext_vector_type(4)));

__device__ inline short f2bf(float x) {
    union { float f; unsigned u; } v; v.f = x;
    unsigned r = v.u + 0x7fffu + ((v.u >> 16) & 1u);   // RNE
    return (short)(r >> 16);
}

__device__ inline unsigned cvt_pk_bf16(float lo, float hi) {
    unsigned r;
    asm("v_cvt_pk_bf16_f32 %0, %1, %2" : "=v"(r) : "v"(lo), "v"(hi));
    return r;
}

__device__ inline void gload_lds16(const u16* g, short* l) {
    __builtin_amdgcn_global_load_lds(
        (const __attribute__((address_space(1))) unsigned int*)g,
        (__attribute__((address_space(3))) unsigned int*)l, 16, 0, 0);
}

// Fused GroupNorm stats + affine + transpose: X[b][c][s] fp32 -> Xn_t[b][s][c] bf16.
__global__ __launch_bounds__(512) void gnx_kernel(
    const float* __restrict__ X, const float* __restrict__ nw,
    const float* __restrict__ nb, u16* __restrict__ Xn_t)
{
    const int blk = blockIdx.x;
    const int bi = blk >> 5, g = blk & 31;
    const int tid = threadIdx.x;
    __shared__ __attribute__((aligned(16))) float T[16][1032];
    __shared__ float red[16];
    __shared__ float sh_mr[2];

    const float* Xg = X + ((size_t)bi * C + g * 16) * S;
    float s = 0.f, ss = 0.f;
    #pragma unroll
    for (int r = 0; r < 8; ++r) {
        int idx4 = r * 512 + tid;
        f32x4 v = *(const f32x4*)(Xg + (size_t)idx4 * 4);
        int c = idx4 >> 8, sp = (idx4 * 4) & 1023;
        *(f32x4*)&T[c][sp] = v;
        s  += v[0] + v[1] + v[2] + v[3];
        ss += v[0]*v[0] + v[1]*v[1] + v[2]*v[2] + v[3]*v[3];
    }
    #pragma unroll
    for (int m = 1; m <= 32; m <<= 1) {
        s += __shfl_xor(s, m); ss += __shfl_xor(ss, m);
    }
    if ((tid & 63) == 0) { red[tid >> 6] = s; red[8 + (tid >> 6)] = ss; }
    __syncthreads();
    if (tid == 0) {
        float S1 = 0.f, S2 = 0.f;
        #pragma unroll
        for (int w = 0; w < 8; ++w) { S1 += red[w]; S2 += red[8 + w]; }
        float mean = S1 * (1.f / 16384.f);
        float var  = S2 * (1.f / 16384.f) - mean * mean;
        sh_mr[0] = mean; sh_mr[1] = rsqrtf(var + 1e-5f);
    }
    __syncthreads();
    const float mean = sh_mr[0], rstd = sh_mr[1];
    float rw[16], sb[16];
    #pragma unroll
    for (int c = 0; c < 16; ++c) {
        float w = nw[g * 16 + c], b = nb[g * 16 + c];
        rw[c] = rstd * w;
        sb[c] = b - mean * rw[c];
    }
    #pragma unroll
    for (int r = 0; r < 2; ++r) {
        int sp = r * 512 + tid;
        bf16x8 o0, o1;
        #pragma unroll
        for (int c = 0; c < 8; ++c) o0[c] = f2bf(T[c][sp] * rw[c] + sb[c]);
        #pragma unroll
        for (int c = 0; c < 8; ++c) o1[c] = f2bf(T[8 + c][sp] * rw[8 + c] + sb[8 + c]);
        u16* dst = Xn_t + ((size_t)bi * S + sp) * C + g * 16;
        *(bf16x8*)dst = o0;
        *(bf16x8*)(dst + 8) = o1;
    }
}

__global__ __launch_bounds__(256) void wconv2(
    const float* __restrict__ wq, const float* __restrict__ wp,
    u16* __restrict__ oq, u16* __restrict__ op)
{
    int i = blockIdx.x * 256 + threadIdx.x;
    const float* w; u16* o; int j;
    if (i < 98304) { w = wq; o = oq; j = i; }
    else           { w = wp; o = op; j = i - 98304; }
    f32x4 a = *(const f32x4*)(w + (size_t)j * 8);
    f32x4 b = *(const f32x4*)(w + (size_t)j * 8 + 4);
    bf16x8 r;
    #pragma unroll
    for (int k = 0; k < 4; ++k) { r[k] = f2bf(a[k]); r[4 + k] = f2bf(b[k]); }
    *(bf16x8*)(o + (size_t)j * 8) = r;
}

// GEMM: A[M][K] bf16 x Bt[N][K] bf16. 128x128 tile, BK=32, 4 waves.
// 3-buffer LDS, counted vmcnt(4): tile kt+2's loads stay in flight across
// the barrier; tile kt+1 guaranteed landed (per-thread loads complete in order).
__global__ __launch_bounds__(256) void qkv_mfma(
    const u16* __restrict__ A, const u16* __restrict__ Bt,
    const float* __restrict__ bias,
    u16* __restrict__ Qt, u16* __restrict__ Kt, u16* __restrict__ Vn)
{
    const int n0 = blockIdx.x * 128, m0 = blockIdx.y * 128;
    const int bi = blockIdx.z;
    const int tid = threadIdx.x, wave = tid >> 6, lane = tid & 63;
    const int lr = lane & 15, lg = lane >> 4;
    const int wr = wave >> 1, wc = wave & 1;

    __shared__ __attribute__((aligned(16))) short SM[3][8][1024];

    f32x4 acc[4][4];
    #pragma unroll
    for (int i = 0; i < 4; ++i)
        #pragma unroll
        for (int j = 0; j < 4; ++j) acc[i][j] = (f32x4){0.f, 0.f, 0.f, 0.f};

    const u16* aP0 = A + (size_t)(m0 + wave * 16 + lr) * C + lg * 8;
    const u16* aP1 = A + (size_t)(m0 + (wave + 4) * 16 + lr) * C + lg * 8;
    const u16* bP0 = Bt + (size_t)bi * S * C + (size_t)(n0 + wave * 16 + lr) * C + lg * 8;
    const u16* bP1 = Bt + (size_t)bi * S * C + (size_t)(n0 + (wave + 4) * 16 + lr) * C + lg * 8;

    auto STAGE = [&](int buf, int t) {
        const int k0 = t * 32;
        gload_lds16(aP0 + k0, &SM[buf][wave][0]);
        gload_lds16(aP1 + k0, &SM[buf][wave + 4][0]);
        gload_lds16(bP0 + k0, &SM[buf][wave][512]);
        gload_lds16(bP1 + k0, &SM[buf][wave + 4][512]);
    };

    STAGE(0, 0);
    STAGE(1, 1);
    asm volatile("s_waitcnt vmcnt(4)" ::: "memory");
    __builtin_amdgcn_s_barrier();
    __builtin_amdgcn_sched_barrier(0);

    #pragma unroll
    for (int kt = 0; kt < 16; ++kt) {
        const int cur = kt % 3;
        if (kt < 14) STAGE((kt + 2) % 3, kt + 2);
        bf16x8 af[4], bfr[4];
        #pragma unroll
        for (int mf = 0; mf < 4; ++mf) af[mf] = *(bf16x8*)&SM[cur][wr * 4 + mf][lane * 8];
        #pragma unroll
        for (int nf = 0; nf < 4; ++nf) bfr[nf] = *(bf16x8*)&SM[cur][wc * 4 + nf][512 + lane * 8];
        __builtin_amdgcn_s_setprio(1);
        #pragma unroll
        for (int mf = 0; mf < 4; ++mf)
            #pragma unroll
            for (int nf = 0; nf < 4; ++nf)
                acc[mf][nf] = __builtin_amdgcn_mfma_f32_16x16x32_bf16(
                    af[mf], bfr[nf], acc[mf][nf], 0, 0, 0);
        __builtin_amdgcn_s_setprio(0);
        if (kt < 15) {
            if (kt < 14) asm volatile("s_waitcnt vmcnt(4)" ::: "memory");
            else         asm volatile("s_waitcnt vmcnt(0)" ::: "memory");
            __builtin_amdgcn_s_barrier();
            __builtin_amdgcn_sched_barrier(0);
        }
    }

    const float QSCALE = 0.125f * 1.44269504088896f;   // exp2-domain scores
    if (m0 < 1024) {
        #pragma unroll
        for (int mf = 0; mf < 4; ++mf) {
            const int o3b = m0 + wr * 64 + mf * 16 + 4 * lg;
            float bv[4];
            #pragma unroll
            for (int i = 0; i < 4; ++i) bv[i] = bias[o3b + i];
            #pragma unroll
            for (int nf = 0; nf < 4; ++nf) {
                const int s = n0 + wc * 64 + nf * 16 + lr;
                if (m0 < 512) {          // Q -> Qt[b][h][s][d], scaled
                    int h = o3b >> 6, d = o3b & 63;
                    u16x4 pk;
                    #pragma unroll
                    for (int i = 0; i < 4; ++i)
                        pk[i] = (u16)f2bf((acc[mf][nf][i] + bv[i]) * QSCALE);
                    *(u16x4*)(Qt + (((size_t)bi * 8 + h) * S + s) * 64 + d) = pk;
                } else {                 // K -> Kt[b][h][s][d]
                    int ok = o3b - 512;
                    int h = ok >> 6, d = ok & 63;
                    u16x4 pk;
                    #pragma unroll
                    for (int i = 0; i < 4; ++i) pk[i] = (u16)f2bf(acc[mf][nf][i] + bv[i]);
                    *(u16x4*)(Kt + (((size_t)bi * 8 + h) * S + s) * 64 + d) = pk;
                }
            }
        }
    } else {
        // V: transpose in LDS (post-loop, buffers free) -> coalesced [d][s] stores
        __syncthreads();
        short* Ts = &SM[0][0][0];   // [128][128] bf16, XOR-swizzled columns
        #pragma unroll
        for (int mf = 0; mf < 4; ++mf) {
            const int orl = wr * 64 + mf * 16 + 4 * lg;
            float bv[4];
            #pragma unroll
            for (int i = 0; i < 4; ++i) bv[i] = bias[m0 + orl + i];
            #pragma unroll
            for (int nf = 0; nf < 4; ++nf) {
                const int srl = wc * 64 + nf * 16 + lr;
                #pragma unroll
                for (int i = 0; i < 4; ++i) {
                    int o = orl + i;
                    Ts[o * 128 + (srl ^ ((o & 7) << 3))] =
                        (short)f2bf(acc[mf][nf][i] + bv[i]);
                }
            }
        }
        __syncthreads();
        const int o = tid >> 1, half = (tid & 1) * 64;
        const int x = (o & 7) << 3;
        const int ov0 = m0 - 1024;
        u16* vdst = Vn + (size_t)(bi * C + ov0 + o) * S + n0 + half;
        #pragma unroll
        for (int c = 0; c < 8; ++c)
            *(bf16x8*)(vdst + 8 * c) = *(bf16x8*)&Ts[o * 128 + ((half + 8 * c) ^ x)];
    }
}

// Attention, swapped operands, exp2 domain (unchanged from round 7).
__global__ __launch_bounds__(512) void attn_mfma(
    const u16* __restrict__ Qt, const u16* __restrict__ Kt,
    const u16* __restrict__ Vn, u16* __restrict__ At)
{
    const int bh = blockIdx.x, qb = blockIdx.y;
    const int bi = bh >> 3, h = bh & 7;
    const int tid = threadIdx.x, wave = tid >> 6, lane = tid & 63;
    const int lr = lane & 15, lg = lane >> 4;
    const int q0 = qb * 128 + wave * 16;

    const u16* qt = Qt + ((size_t)bi * 8 + h) * S * 64;
    const u16* kp = Kt + ((size_t)bi * 8 + h) * S * 64;
    const u16* vp = Vn + (size_t)(bi * C + h * 64) * S;

    __shared__ __attribute__((aligned(16))) short Ks[2][4096];
    __shared__ __attribute__((aligned(16))) short Vs[2][4096];
    __shared__ __attribute__((aligned(16))) short Pw[8][16][64];

    bf16x8 aq0 = *(const bf16x8*)(qt + (size_t)(q0 + lr) * 64 + lg * 8);
    bf16x8 aq1 = *(const bf16x8*)(qt + (size_t)(q0 + lr) * 64 + 32 + lg * 8);

    float mrun = -1e30f, lrun = 0.f;
    f32x4 acc[4];
    #pragma unroll
    for (int df = 0; df < 4; ++df) acc[df] = (f32x4){0.f, 0.f, 0.f, 0.f};

    auto STAGE = [&](int buf, int kt0) {
        int r = tid >> 3, cs = (tid & 7) ^ (r & 7);
        short* ldsK = &Ks[buf][(wave << 6) * 8];
        short* ldsV = &Vs[buf][(wave << 6) * 8];
        gload_lds16(kp + (size_t)(kt0 + r) * 64 + cs * 8, ldsK);
        gload_lds16(vp + (size_t)r * S + kt0 + cs * 8, ldsV);
    };

    unsigned* pwb = (unsigned*)&Pw[wave][0][0];
    const int rsw = lr & 7;

    STAGE(0, 0);
    __syncthreads();

    for (int kt = 0; kt < 16; ++kt) {
        const int cur = kt & 1;
        if (kt < 15) STAGE(cur ^ 1, (kt + 1) * 64);

        f32x4 sc[4];
        __builtin_amdgcn_s_setprio(1);
        #pragma unroll
        for (int kf = 0; kf < 4; ++kf) {
            int rK = kf * 16 + lr;
            bf16x8 b0 = *(bf16x8*)&Ks[cur][rK * 64 + (lg ^ (rK & 7)) * 8];
            bf16x8 b1 = *(bf16x8*)&Ks[cur][rK * 64 + ((lg + 4) ^ (rK & 7)) * 8];
            f32x4 z = (f32x4){0.f, 0.f, 0.f, 0.f};
            z = __builtin_amdgcn_mfma_f32_16x16x32_bf16(b0, aq0, z, 0, 0, 0);
            sc[kf] = __builtin_amdgcn_mfma_f32_16x16x32_bf16(b1, aq1, z, 0, 0, 0);
        }
        __builtin_amdgcn_s_setprio(0);

        float tmax = sc[0][0];
        #pragma unroll
        for (int kf = 0; kf < 4; ++kf)
            #pragma unroll
            for (int i = 0; i < 4; ++i) tmax = fmaxf(tmax, sc[kf][i]);
        tmax = fmaxf(tmax, __shfl_xor(tmax, 16));
        tmax = fmaxf(tmax, __shfl_xor(tmax, 32));

        if (!__all(tmax <= mrun + 8.f)) {
            float mnew = fmaxf(mrun, tmax);
            float fac = __builtin_amdgcn_exp2f(mrun - mnew);
            mrun = mnew;
            lrun *= fac;
            #pragma unroll
            for (int df = 0; df < 4; ++df) acc[df] *= fac;
        }

        float sum = 0.f;
        #pragma unroll
        for (int kf = 0; kf < 4; ++kf)
            #pragma unroll
            for (int i = 0; i < 4; ++i) {
                sc[kf][i] = __builtin_amdgcn_exp2f(sc[kf][i] - mrun);
                sum += sc[kf][i];
            }

        #pragma unroll
        for (int kf = 0; kf < 4; ++kf) {
            unsigned p0 = cvt_pk_bf16(sc[kf][0], sc[kf][1]);
            unsigned p1 = cvt_pk_bf16(sc[kf][2], sc[kf][3]);
            int c0 = kf * 8 + 2 * lg;
            int idx = lr * 32 + ((c0 >> 2) ^ rsw) * 4 + (c0 & 3);
            *(u32x2*)&pwb[idx] = (u32x2){p0, p1};
        }

        sum += __shfl_xor(sum, 16);
        sum += __shfl_xor(sum, 32);
        lrun += sum;

        bf16x8 pb0 = *(bf16x8*)&Pw[wave][lr][(lg ^ rsw) * 8];
        bf16x8 pb1 = *(bf16x8*)&Pw[wave][lr][((4 + lg) ^ rsw) * 8];
        __builtin_amdgcn_s_setprio(1);
        #pragma unroll
        for (int df = 0; df < 4; ++df) {
            int rV = df * 16 + lr;
            bf16x8 v0 = *(bf16x8*)&Vs[cur][rV * 64 + (lg ^ (rV & 7)) * 8];
            bf16x8 v1 = *(bf16x8*)&Vs[cur][rV * 64 + ((lg + 4) ^ (rV & 7)) * 8];
            acc[df] = __builtin_amdgcn_mfma_f32_16x16x32_bf16(v0, pb0, acc[df], 0, 0, 0);
            acc[df] = __builtin_amdgcn_mfma_f32_16x16x32_bf16(v1, pb1, acc[df], 0, 0, 0);
        }
        __builtin_amdgcn_s_setprio(0);
        __syncthreads();
    }

    float linv = 1.f / lrun;
    #pragma unroll
    for (int df = 0; df < 4; ++df) {
        u16x4 pk;
        #pragma unroll
        for (int i = 0; i < 4; ++i) pk[i] = (u16)f2bf(acc[df][i] * linv);
        *(u16x4*)(At + ((size_t)bi * S + q0 + lr) * C + h * 64 + df * 16 + 4 * lg) = pk;
    }
}

// proj: A=Wp[512][512] x Bt=attn_t[s][c] + bias + residual -> fp32 out.
// Same 3-buffer counted-vmcnt pipeline as qkv.
__global__ __launch_bounds__(256) void proj_mfma(
    const u16* __restrict__ A, const u16* __restrict__ Bt,
    const float* __restrict__ bias, const float* __restrict__ Xres,
    float* __restrict__ out)
{
    const int n0 = blockIdx.x * 128, m0 = blockIdx.y * 128;
    const int bi = blockIdx.z;
    const int tid = threadIdx.x, wave = tid >> 6, lane = tid & 63;
    const int lr = lane & 15, lg = lane >> 4;
    const int wr = wave >> 1, wc = wave & 1;

    __shared__ __attribute__((aligned(16))) short SM[3][8][1024];

    f32x4 acc[4][4];
    #pragma unroll
    for (int i = 0; i < 4; ++i)
        #pragma unroll
        for (int j = 0; j < 4; ++j) acc[i][j] = (f32x4){0.f, 0.f, 0.f, 0.f};

    const u16* aP0 = A + (size_t)(m0 + wave * 16 + lr) * C + lg * 8;
    const u16* aP1 = A + (size_t)(m0 + (wave + 4) * 16 + lr) * C + lg * 8;
    const u16* bP0 = Bt + (size_t)bi * S * C + (size_t)(n0 + wave * 16 + lr) * C + lg * 8;
    const u16* bP1 = Bt + (size_t)bi * S * C + (size_t)(n0 + (wave + 4) * 16 + lr) * C + lg * 8;

    auto STAGE = [&](int buf, int t) {
        const int k0 = t * 32;
        gload_lds16(aP0 + k0, &SM[buf][wave][0]);
        gload_lds16(aP1 + k0, &SM[buf][wave + 4][0]);
        gload_lds16(bP0 + k0, &SM[buf][wave][512]);
        gload_lds16(bP1 + k0, &SM[buf][wave + 4][512]);
    };

    STAGE(0, 0);
    STAGE(1, 1);
    asm volatile("s_waitcnt vmcnt(4)" ::: "memory");
    __builtin_amdgcn_s_barrier();
    __builtin_amdgcn_sched_barrier(0);

    #pragma unroll
    for (int kt = 0; kt < 16; ++kt) {
        const int cur = kt % 3;
        if (kt < 14) STAGE((kt + 2) % 3, kt + 2);
        bf16x8 af[4], bfr[4];
        #pragma unroll
        for (int mf = 0; mf < 4; ++mf) af[mf] = *(bf16x8*)&SM[cur][wr * 4 + mf][lane * 8];
        #pragma unroll
        for (int nf = 0; nf < 4; ++nf) bfr[nf] = *(bf16x8*)&SM[cur][wc * 4 + nf][512 + lane * 8];
        __builtin_amdgcn_s_setprio(1);
        #pragma unroll
        for (int mf = 0; mf < 4; ++mf)
            #pragma unroll
            for (int nf = 0; nf < 4; ++nf)
                acc[mf][nf] = __builtin_amdgcn_mfma_f32_16x16x32_bf16(
                    af[mf], bfr[nf], acc[mf][nf], 0, 0, 0);
        __builtin_amdgcn_s_setprio(0);
        if (kt < 15) {
            if (kt < 14) asm volatile("s_waitcnt vmcnt(4)" ::: "memory");
            else         asm volatile("s_waitcnt vmcnt(0)" ::: "memory");
            __builtin_amdgcn_s_barrier();
            __builtin_amdgcn_sched_barrier(0);
        }
    }

    #pragma unroll
    for (int mf = 0; mf < 4; ++mf) {
        const int ob = m0 + wr * 64 + mf * 16 + 4 * lg;
        float bv[4];
        #pragma unroll
        for (int i = 0; i < 4; ++i) bv[i] = bias[ob + i];
        #pragma unroll
        for (int nf = 0; nf < 4; ++nf) {
            const int s = n0 + wc * 64 + nf * 16 + lr;
            #pragma unroll
            for (int i = 0; i < 4; ++i) {
                size_t oi = ((size_t)bi * C + ob + i) * S + s;
                out[oi] = acc[mf][nf][i] + bv[i] + Xres[oi];
            }
        }
    }
}

extern "C" void kernel_launch(void* const* d_in, const int* in_sizes, int n_in,
                              void* d_out, int out_size, void* d_ws, size_t ws_size,
                              hipStream_t stream) {
    const float* X      = (const float*)d_in[0];
    const float* norm_w = (const float*)d_in[1];
    const float* norm_b = (const float*)d_in[2];
    const float* qkv_w  = (const float*)d_in[3];
    const float* qkv_b  = (const float*)d_in[4];
    const float* proj_w = (const float*)d_in[5];
    const float* proj_b = (const float*)d_in[6];
    float* out = (float*)d_out;

    u16* Wq_bf = (u16*)d_ws;                   // 1536*512
    u16* Wp_bf = Wq_bf + 786432;               // 512*512
    u16* Xn_t  = Wp_bf + 262144;               // 8*1024*512
    u16* Qt    = Xn_t + 4194304;               // 8*8*1024*64
    u16* Kt    = Qt + 4194304;
    u16* Vn    = Kt + 4194304;                 // 8*512*1024
    u16* At    = Vn + 4194304;                 // 8*1024*512

    gnx_kernel<<<dim3(BATCH * 32), 512, 0, stream>>>(X, norm_w, norm_b, Xn_t);
    wconv2<<<dim3(512), 256, 0, stream>>>(qkv_w, proj_w, Wq_bf, Wp_bf);
    qkv_mfma<<<dim3(S / 128, OC3 / 128, BATCH), 256, 0, stream>>>(
        Wq_bf, Xn_t, qkv_b, Qt, Kt, Vn);
    attn_mfma<<<dim3(64, S / 128), 512, 0, stream>>>(Qt, Kt, Vn, At);
    proj_mfma<<<dim3(S / 128, C / 128, BATCH), 256, 0, stream>>>(
        Wp_bf, At, proj_b, X, out);
}